// Round 7
// baseline (45.936 us; speedup 1.0000x reference)
//
#include <hip/hip_runtime.h>
#include <hip/hip_bf16.h>

#define B_ 4
#define C_ 64
#define H_ 128
#define W_ 128
#define HW_ (H_ * W_)
#define OCH_ 18

typedef __attribute__((ext_vector_type(8))) short short8;
typedef __attribute__((ext_vector_type(16))) float f32x16;
typedef __attribute__((ext_vector_type(2))) float float2v;

// ws layout (bytes):
//   [0, 73728)                      w2b: main weights, A-frag order (bf16)
//   [73728, 110592)                 w2a: offset-conv weights, A-frag order (bf16)
//   [131072, 131072+2359296)        offsets buffer (fallback path only)
//   [2490368, 2490368+8388608)      xh : x in NHWC bf16, [b][h][w][c]
#define W2B_ELEMS (9 * 2 * 4 * 64 * 8)   // 36864
#define W2A_ELEMS (36 * 64 * 8)          // 18432
#define OFF_BYTE_OFS 131072
#define XH_BYTE_OFS  2490368
#define WS_NEED (XH_BYTE_OFS + (size_t)B_ * H_ * W_ * C_ * 2)

// LDS window: 4 chunk-planes (8ch) x 5 rows x 72 cols x 16B, padded plane stride
#define WCOLS 72
#define PSTRIDE_B (5 * WCOLS * 16 + 16)   // 5776 (stride % 128B != 0)
#define WIN_BYTES (4 * PSTRIDE_B)         // 23104

__device__ __forceinline__ unsigned short f2bf(float f) {
  union { float f; unsigned u; } v; v.f = f;
  unsigned r = v.u + 0x7FFFu + ((v.u >> 16) & 1u);   // RNE
  return (unsigned short)(r >> 16);
}
__device__ __forceinline__ float bf2f(unsigned short h) {
  union { unsigned u; float f; } v; v.u = ((unsigned)h) << 16;
  return v.f;
}
__device__ __forceinline__ unsigned short f2bfh(float f) {   // hot path: HW cvt
  __hip_bfloat16 h = __float2bfloat16(f);
  return *reinterpret_cast<unsigned short*>(&h);
}
__device__ __forceinline__ float uaf(unsigned u) {
  union { unsigned u; float f; } v; v.u = u; return v.f;
}
// bijective XCD swizzles
__device__ __forceinline__ int swz512(int x)  { return (x & 7) * 64  + (x >> 3); }
__device__ __forceinline__ int swz1024(int x) { return (x & 7) * 128 + (x >> 3); }

// ---------------- weight pack (shared by both paths) ----------------
__device__ __forceinline__ void pack_weights_body(
    int idx, const float* __restrict__ wmain, const float* __restrict__ offw,
    unsigned short* __restrict__ ws_u) {
  if (idx < W2B_ELEMS) {
    int i = idx & 7, lane = (idx >> 3) & 63, s = (idx >> 9) & 3;
    int mq = (idx >> 11) & 1, t = idx >> 12;
    int o = mq * 32 + (lane & 31);
    int c = 16 * s + (lane >> 5) * 8 + i;
    ws_u[idx] = f2bf(wmain[(o * 64 + c) * 9 + t]);
  } else if (idx < W2B_ELEMS + W2A_ELEMS) {
    int j = idx - W2B_ELEMS;
    int i = j & 7, lane = (j >> 3) & 63, s = j >> 9;   // s 0..35
    int kg = 16 * s + (lane >> 5) * 8 + i;
    int t = kg >> 6, c = kg & 63, oc = lane & 31;
    ws_u[idx] = (oc < OCH_) ? f2bf(offw[(oc * 64 + c) * 9 + t]) : (unsigned short)0;
  }
}

// ---------------- prep kernel: NHWC repack (blocks 0..511) + weight pack (512+) ----------
__global__ __launch_bounds__(256) void prep_kernel(
    const float* __restrict__ x, const float* __restrict__ wmain,
    const float* __restrict__ offw, unsigned short* __restrict__ ws_u,
    unsigned short* __restrict__ xh) {
  const int tid = threadIdx.x;
  if (blockIdx.x < 512) {
    __shared__ float s[W_ * 65];
    const int h = blockIdx.x & (H_ - 1);
    const int b = blockIdx.x >> 7;
    const float* xb = x + ((size_t)b * C_ * H_ + h) * W_;
    for (int i = tid; i < C_ * W_; i += 256) {
      int c = i >> 7, w = i & (W_ - 1);
      s[w * 65 + c] = xb[(size_t)c * HW_ + w];
    }
    __syncthreads();
    unsigned short* dst = xh + ((size_t)(b * H_ + h) * W_) * C_;
    for (int i = tid; i < W_ * 8; i += 256) {
      int w = i >> 3, g = i & 7;
      short8 v;
      #pragma unroll
      for (int j = 0; j < 8; ++j) v[j] = (short)f2bf(s[w * 65 + g * 8 + j]);
      *(short8*)&dst[w * C_ + g * 8] = v;
    }
  } else {
    pack_weights_body((blockIdx.x - 512) * 256 + tid, wmain, offw, ws_u);
  }
}

__global__ __launch_bounds__(256) void pack_w_only(
    const float* __restrict__ wmain, const float* __restrict__ offw,
    unsigned short* __restrict__ ws_u) {
  pack_weights_body(blockIdx.x * 256 + threadIdx.x, wmain, offw, ws_u);
}

// ---------------- per-tap deform+MFMA body (window gather, packed-f32 blend) ------------
template<int KI, int KJ, int CPH>
__device__ __forceinline__ void tap_body(
    float dy, float dx, int ho, int wo0, int px, int lane, int b,
    const char* __restrict__ win, const unsigned short* __restrict__ xh,
    const unsigned short* __restrict__ wt2,   // w2b + tap*4096
    f32x16& acc0, f32x16& acc1) {
  const float ys = (float)(ho - 1 + KI) + dy;
  const float xs = (float)(px - 1 + KJ) + dx;
  const float y0f = floorf(ys), x0f = floorf(xs);
  const int y0 = (int)y0f, x0 = (int)x0f;
  const int y1 = y0 + 1, x1 = x0 + 1;
  const float wy1 = ys - y0f, wx1 = xs - x0f;
  const float wy0 = 1.f - wy1, wx0 = 1.f - wx1;
  const bool vy0 = (unsigned)y0 < (unsigned)H_, vy1 = (unsigned)y1 < (unsigned)H_;
  const bool vx0 = (unsigned)x0 < (unsigned)W_, vx1 = (unsigned)x1 < (unsigned)W_;
  const float g00 = (vy0 && vx0) ? wy0 * wx0 : 0.f;
  const float g01 = (vy0 && vx1) ? wy0 * wx1 : 0.f;
  const float g10 = (vy1 && vx0) ? wy1 * wx0 : 0.f;
  const float g11 = (vy1 && vx1) ? wy1 * wx1 : 0.f;
  const int yc0 = min(max(y0, 0), H_ - 1), yc1 = min(max(y1, 0), H_ - 1);
  const int xc0 = min(max(x0, 0), W_ - 1), xc1 = min(max(x1, 0), W_ - 1);
  const int rr0 = yc0 - ho + 2, rr1 = yc1 - ho + 2;
  const int cc0 = xc0 - wo0 + 4, cc1 = xc1 - wo0 + 4;
  const bool inw = ((unsigned)rr0 < 5u) & ((unsigned)rr1 < 5u) &
                   ((unsigned)cc0 < (unsigned)WCOLS) & ((unsigned)cc1 < (unsigned)WCOLS);
  const int r0 = min(max(rr0, 0), 4), r1 = min(max(rr1, 0), 4);
  const int c0 = min(max(cc0, 0), WCOLS - 1), c1 = min(max(cc1, 0), WCOLS - 1);
  const int u00 = (r0 * WCOLS + c0) << 4, u01 = (r0 * WCOLS + c1) << 4;
  const int u10 = (r1 * WCOLS + c0) << 4, u11 = (r1 * WCOLS + c1) << 4;
  const int laneh = lane >> 5;
  #pragma unroll
  for (int ssl = 0; ssl < 2; ++ssl) {
    const int ss = CPH * 2 + ssl;
    const char* pb = win + (2 * ssl + laneh) * PSTRIDE_B;
    short8 c00 = *(const short8*)(pb + u00);
    short8 c01 = *(const short8*)(pb + u01);
    short8 c10 = *(const short8*)(pb + u10);
    short8 c11 = *(const short8*)(pb + u11);
    if (!inw) {                                   // rare (|dy| or |dx| >= ~1)
      const size_t ch8 = (size_t)((2 * ss + laneh) << 3);
      c00 = *(const short8*)&xh[(((size_t)((b * H_ + yc0) * W_ + xc0)) << 6) + ch8];
      c01 = *(const short8*)&xh[(((size_t)((b * H_ + yc0) * W_ + xc1)) << 6) + ch8];
      c10 = *(const short8*)&xh[(((size_t)((b * H_ + yc1) * W_ + xc0)) << 6) + ch8];
      c11 = *(const short8*)&xh[(((size_t)((b * H_ + yc1) * W_ + xc1)) << 6) + ch8];
    }
    short8 bf;
    #pragma unroll
    for (int d = 0; d < 4; ++d) {                 // packed 2-wide f32 blend per dword
      const unsigned w00 = ((const unsigned*)&c00)[d];
      const unsigned w01 = ((const unsigned*)&c01)[d];
      const unsigned w10 = ((const unsigned*)&c10)[d];
      const unsigned w11 = ((const unsigned*)&c11)[d];
      float2v p00, p01, p10, p11;
      p00.x = uaf(w00 << 16); p00.y = uaf(w00 & 0xFFFF0000u);
      p01.x = uaf(w01 << 16); p01.y = uaf(w01 & 0xFFFF0000u);
      p10.x = uaf(w10 << 16); p10.y = uaf(w10 & 0xFFFF0000u);
      p11.x = uaf(w11 << 16); p11.y = uaf(w11 & 0xFFFF0000u);
      float2v v = p00 * g00 + p01 * g01 + p10 * g10 + p11 * g11;
      ((unsigned*)&bf)[d] = (unsigned)f2bfh(v.x) | ((unsigned)f2bfh(v.y) << 16);
    }
    const short8 a0 = *(const short8*)&wt2[(ss * 64 + lane) * 8];
    const short8 a1 = *(const short8*)&wt2[((4 + ss) * 64 + lane) * 8];
    acc0 = __builtin_amdgcn_mfma_f32_32x32x16_bf16(a0, bf, acc0, 0, 0, 0);
    acc1 = __builtin_amdgcn_mfma_f32_32x32x16_bf16(a1, bf, acc1, 0, 0, 0);
  }
}

#define NLOAD (4 * 5 * WCOLS)   // 1440 short8 loads per stage

// stage 4 chunk-planes (channels 32*CPH..+31) of rows ho-2..ho+2, cols wo0-4..wo0+67
#define STAGEW(CPH)                                                                     \
  _Pragma("unroll")                                                                     \
  for (int it = 0; it < 6; ++it) {                                                      \
    const int i = tid + it * 256;                                                       \
    if (i < NLOAD) {                                                                    \
      const int p = i & 3;                                                              \
      const int j = i >> 2;                                                             \
      const int col = j % WCOLS;                                                        \
      const int r = j / WCOLS;                                                          \
      const int srow = min(H_ - 1, max(0, ho - 2 + r));                                 \
      const int scol = min(W_ - 1, max(0, wo0 - 4 + col));                              \
      const short8 v = *(const short8*)&xh[(((size_t)((b * H_ + srow) * W_ + scol)) << 6) \
                                           + ((4 * (CPH) + p) << 3)];                   \
      *(short8*)(smem + p * PSTRIDE_B + ((r * WCOLS + col) << 4)) = v;                  \
    }                                                                                   \
  }

// offset-conv half: 18 K-steps with (s&3) in {2*CPH, 2*CPH+1}, read from window
#define P1HALF(CPH)                                                                     \
  _Pragma("unroll")                                                                     \
  for (int t = 0; t < 9; ++t) {                                                         \
    _Pragma("unroll")                                                                   \
    for (int q = 0; q < 2; ++q) {                                                       \
      const int s = 4 * t + 2 * (CPH) + q;                                              \
      const int ki = t / 3, kj = t - 3 * (t / 3);                                       \
      const int row = ho - 1 + ki, col = px - 1 + kj;                                   \
      short8 bfr = {0, 0, 0, 0, 0, 0, 0, 0};                                            \
      if (((unsigned)row < (unsigned)H_) && ((unsigned)col < (unsigned)W_))             \
        bfr = *(const short8*)(smem + (2 * q + laneh) * PSTRIDE_B                       \
                               + (((ki + 1) * WCOLS + (pxl + 3 + kj)) << 4));           \
      const short8 afr = *(const short8*)&w2a[((size_t)s * 64 + lane) * 8];             \
      pacc = __builtin_amdgcn_mfma_f32_32x32x16_bf16(afr, bfr, pacc, 0, 0, 0);          \
    }                                                                                   \
  }

// extract dy/dx for tap T from pacc (C/D layout: row=oc=(reg&3)+8*(reg>>2)+4h, col=px)
#define EXT(T, J)                                                                       \
  {                                                                                     \
    constexpr int ocy = 2 * (T), ocx = 2 * (T) + 1;                                     \
    constexpr int ry = (ocy & 3) + 4 * (ocy >> 3), hy = (ocy >> 2) & 1;                 \
    constexpr int rx = (ocx & 3) + 4 * (ocx >> 3), hx = (ocx >> 2) & 1;                 \
    dys[J] = __shfl(pacc[ry], (lane & 31) + (hy << 5)) + ob[ocy];                       \
    dxs[J] = __shfl(pacc[rx], (lane & 31) + (hx << 5)) + ob[ocx];                       \
  }

#define TAP(KI, KJ, CPH, J)                                                             \
  tap_body<KI, KJ, CPH>(dys[J], dxs[J], ho, wo0, px, lane, b, smem, xh,                 \
                        w2b + ((KI) * 3 + (KJ)) * 4096, acc0, acc1)

#define P2CPH(CPH)                                                                      \
  if (sub == 0) {                                                                       \
    TAP(0, 0, CPH, 0); TAP(0, 1, CPH, 1); TAP(0, 2, CPH, 2); TAP(1, 0, CPH, 3);         \
  } else {                                                                              \
    TAP(1, 1, CPH, 0); TAP(1, 2, CPH, 1); TAP(2, 0, CPH, 2); TAP(2, 1, CPH, 3);         \
    TAP(2, 2, CPH, 4);                                                                  \
  }

// ---------------- fused kernel v3: half-row blocks, packed blend ----------------
// block=(b,ho,whalf): 1024 blocks x 256 threads (4 waves = 2 pairs x 2 subs).
// phase 1: offset conv from window (duplicate across subs, offsets via shfl)
// phase 2: tap-split (sub0: taps 0-3, sub1: 4-8), window gathers, 2 channel-phases
__global__ __launch_bounds__(256, 4) void deform_fused3(
    const unsigned short* __restrict__ xh, const float* __restrict__ bias,
    const float* __restrict__ ob, const unsigned short* __restrict__ w2b,
    const unsigned short* __restrict__ w2a, float* __restrict__ out) {
  const int blk = swz1024(blockIdx.x);
  const int whalf = blk & 1;
  const int ho = (blk >> 1) & (H_ - 1);
  const int b  = blk >> 8;
  const int wo0 = whalf * 64;
  const int tid = threadIdx.x;
  const int lane = tid & 63;
  const int wave = tid >> 6;
  const int pair = wave >> 1;
  const int sub  = wave & 1;
  const int pxl  = pair * 32 + (lane & 31);   // 0..63 within half-row
  const int px   = wo0 + pxl;
  const int laneh = lane >> 5;

  __shared__ __align__(16) char smem[WIN_BYTES];   // 22.6 KB; reused for reduction

  // ================= phase 1: offset conv =================
  f32x16 pacc;
  #pragma unroll
  for (int r = 0; r < 16; ++r) pacc[r] = 0.f;

  STAGEW(0);
  __syncthreads();
  P1HALF(0);
  __syncthreads();
  STAGEW(1);
  __syncthreads();
  P1HALF(1);

  // offsets for this wave's taps, wave-internal via shfl
  float dys[5], dxs[5];
  if (sub == 0) {
    EXT(0, 0); EXT(1, 1); EXT(2, 2); EXT(3, 3);
    dys[4] = 0.f; dxs[4] = 0.f;
  } else {
    EXT(4, 0); EXT(5, 1); EXT(6, 2); EXT(7, 3); EXT(8, 4);
  }

  // ================= phase 2: deformable sample + einsum =================
  f32x16 acc0, acc1;
  #pragma unroll
  for (int r = 0; r < 16; ++r) { acc0[r] = 0.f; acc1[r] = 0.f; }

  P2CPH(1);                 // window currently holds channels 32..63
  __syncthreads();
  STAGEW(0);
  __syncthreads();
  P2CPH(0);                 // channels 0..31
  __syncthreads();

  // ---- pairwise (sub) reduction in reused window LDS + epilogue ----
  float* red = (float*)smem;
  if (sub) {
    #pragma unroll
    for (int i = 0; i < 16; ++i) {
      red[(i * 2 + pair) * 64 + lane]        = acc0[i];
      red[((16 + i) * 2 + pair) * 64 + lane] = acc1[i];
    }
  }
  __syncthreads();
  if (!sub) {
    #pragma unroll
    for (int i = 0; i < 16; ++i) {
      acc0[i] += red[(i * 2 + pair) * 64 + lane];
      acc1[i] += red[((16 + i) * 2 + pair) * 64 + lane];
    }
    #pragma unroll
    for (int reg = 0; reg < 16; ++reg) {
      int row = (reg & 3) + 8 * (reg >> 2) + 4 * laneh;
      out[((b * 64 + row)      * H_ + ho) * W_ + px] = acc0[reg] + bias[row];
      out[((b * 64 + 32 + row) * H_ + ho) * W_ + px] = acc1[reg] + bias[32 + row];
    }
  }
}

// ================= fallback path (round-3 CHW, used only if ws too small) =================
__global__ __launch_bounds__(256) void offset_conv_mfma(
    const float* __restrict__ x, const float* __restrict__ ob,
    const unsigned short* __restrict__ w2a, unsigned short* __restrict__ offout) {
  const int ho = blockIdx.x & (H_ - 1);
  const int b  = blockIdx.x >> 7;
  const int tid = threadIdx.x;
  const int lane = tid & 63;
  const int wv = tid >> 6;
  __shared__ __align__(16) unsigned short sx[3 * 130 * 64];
  const float* xb = x + (size_t)b * C_ * HW_;
  for (int i = tid; i < 96 * 130; i += 256) {
    int col = i % 130;
    int c2  = i / 130;
    int r   = c2 >> 5;
    int c   = (c2 & 31) * 2;
    int row = ho - 1 + r, gcol = col - 1;
    float v0 = 0.f, v1 = 0.f;
    if ((unsigned)row < (unsigned)H_ && (unsigned)gcol < (unsigned)W_) {
      v0 = xb[(size_t)c * HW_ + row * W_ + gcol];
      v1 = xb[(size_t)(c + 1) * HW_ + row * W_ + gcol];
    }
    unsigned pk = (unsigned)f2bf(v0) | ((unsigned)f2bf(v1) << 16);
    int cblk = (c >> 3) ^ (col & 7);
    int h = ((r * 130 + col) * 8 + cblk) * 8 + (c & 7);
    *(unsigned*)&sx[h] = pk;
  }
  __syncthreads();
  const int px  = wv * 32 + (lane & 31);
  const int cbh = lane >> 5;
  f32x16 acc;
  #pragma unroll
  for (int r = 0; r < 16; ++r) acc[r] = 0.f;
  for (int s = 0; s < 36; ++s) {
    int t  = s >> 2;
    int ki = t / 3, kj = t - 3 * ki;
    int j  = px + kj;
    int cblk = (s & 3) * 2 + cbh;
    const short8 bfr = *(const short8*)&sx[((ki * 130 + j) * 8 + (cblk ^ (j & 7))) * 8];
    const short8 afr = *(const short8*)&w2a[(s * 64 + lane) * 8];
    acc = __builtin_amdgcn_mfma_f32_32x32x16_bf16(afr, bfr, acc, 0, 0, 0);
  }
  #pragma unroll
  for (int reg = 0; reg < 16; ++reg) {
    int oc = (reg & 3) + 8 * (reg >> 2) + 4 * (lane >> 5);
    if (oc < OCH_) {
      float v = acc[reg] + ob[oc];
      offout[((b * OCH_ + oc) * H_ + ho) * W_ + px] = f2bf(v);
    }
  }
}

__global__ __launch_bounds__(256) void deform_mfma(
    const float* __restrict__ x, const float* __restrict__ bias,
    const unsigned short* __restrict__ w2b, const unsigned short* __restrict__ offb,
    float* __restrict__ out) {
  const int ho = blockIdx.x & (H_ - 1);
  const int b  = blockIdx.x >> 7;
  const int lane = threadIdx.x & 63;
  const int wv   = threadIdx.x >> 6;
  const int px   = wv * 32 + (lane & 31);
  const int cb   = (lane >> 5) * 8;
  const float* xb = x + (size_t)b * C_ * HW_;
  f32x16 acc0, acc1;
  #pragma unroll
  for (int r = 0; r < 16; ++r) { acc0[r] = 0.f; acc1[r] = 0.f; }
  for (int t = 0; t < 9; ++t) {
    const int ki = t / 3, kj = t - 3 * ki;
    float dy = bf2f(offb[((b * OCH_ + 2 * t)     * H_ + ho) * W_ + px]);
    float dx = bf2f(offb[((b * OCH_ + 2 * t + 1) * H_ + ho) * W_ + px]);
    float ys = (float)(ho - 1 + ki) + dy;
    float xs = (float)(px - 1 + kj) + dx;
    float y0f = floorf(ys), x0f = floorf(xs);
    int y0 = (int)y0f, x0 = (int)x0f;
    int y1 = y0 + 1,   x1 = x0 + 1;
    float wy1 = ys - y0f, wx1 = xs - x0f;
    float wy0 = 1.f - wy1, wx0 = 1.f - wx1;
    bool vy0 = (unsigned)y0 < (unsigned)H_, vy1 = (unsigned)y1 < (unsigned)H_;
    bool vx0 = (unsigned)x0 < (unsigned)W_, vx1 = (unsigned)x1 < (unsigned)W_;
    int yc0 = min(max(y0, 0), H_ - 1), yc1 = min(max(y1, 0), H_ - 1);
    int xc0 = min(max(x0, 0), W_ - 1), xc1 = min(max(x1, 0), W_ - 1);
    const int o00 = yc0 * W_ + xc0, o01 = yc0 * W_ + xc1;
    const int o10 = yc1 * W_ + xc0, o11 = yc1 * W_ + xc1;
    const float g00 = (vy0 && vx0) ? wy0 * wx0 : 0.f;
    const float g01 = (vy0 && vx1) ? wy0 * wx1 : 0.f;
    const float g10 = (vy1 && vx0) ? wy1 * wx0 : 0.f;
    const float g11 = (vy1 && vx1) ? wy1 * wx1 : 0.f;
    const short8* wp = (const short8*)(w2b + (size_t)t * 2 * 4 * 64 * 8);
    short8 a0[4], a1[4];
    #pragma unroll
    for (int s = 0; s < 4; ++s) {
      a0[s] = wp[s * 64 + lane];
      a1[s] = wp[(4 + s) * 64 + lane];
    }
    #pragma unroll
    for (int s = 0; s < 4; ++s) {
      const int cidx = (cb + 16 * s) * HW_;
      short8 bf;
      #pragma unroll
      for (int i = 0; i < 8; ++i) {
        const int bi = cidx + i * HW_;
        float v = g00 * xb[bi + o00] + g01 * xb[bi + o01]
                + g10 * xb[bi + o10] + g11 * xb[bi + o11];
        bf[i] = (short)f2bf(v);
      }
      acc0 = __builtin_amdgcn_mfma_f32_32x32x16_bf16(a0[s], bf, acc0, 0, 0, 0);
      acc1 = __builtin_amdgcn_mfma_f32_32x32x16_bf16(a1[s], bf, acc1, 0, 0, 0);
    }
  }
  #pragma unroll
  for (int reg = 0; reg < 16; ++reg) {
    int row = (reg & 3) + 8 * (reg >> 2) + 4 * (lane >> 5);
    out[((b * 64 + row)      * H_ + ho) * W_ + px] = acc0[reg] + bias[row];
    out[((b * 64 + 32 + row) * H_ + ho) * W_ + px] = acc1[reg] + bias[32 + row];
  }
}

extern "C" void kernel_launch(void* const* d_in, const int* in_sizes, int n_in,
                              void* d_out, int out_size, void* d_ws, size_t ws_size,
                              hipStream_t stream) {
  const float* x    = (const float*)d_in[0];
  const float* wt   = (const float*)d_in[1];
  const float* bias = (const float*)d_in[2];
  const float* ow   = (const float*)d_in[3];
  const float* ob   = (const float*)d_in[4];
  float* out = (float*)d_out;

  unsigned short* ws_u  = (unsigned short*)d_ws;
  unsigned short* w2b   = ws_u;
  unsigned short* w2a   = ws_u + W2B_ELEMS;
  unsigned short* offbf = (unsigned short*)((char*)d_ws + OFF_BYTE_OFS);
  unsigned short* xh    = (unsigned short*)((char*)d_ws + XH_BYTE_OFS);

  const int pack_blocks = (W2B_ELEMS + W2A_ELEMS + 255) / 256;   // 216

  if (ws_size >= WS_NEED) {
    prep_kernel<<<512 + pack_blocks, 256, 0, stream>>>(x, wt, ow, ws_u, xh);
    deform_fused3<<<1024, 256, 0, stream>>>(xh, bias, ob, w2b, w2a, out);
  } else {
    pack_w_only<<<pack_blocks, 256, 0, stream>>>(wt, ow, ws_u);
    offset_conv_mfma<<<B_ * H_, 256, 0, stream>>>(x, ob, w2a, offbf);
    deform_mfma<<<B_ * H_, 256, 0, stream>>>(x, bias, w2b, offbf, out);
  }
}

// Round 8
// 44.823 us; speedup vs baseline: 1.0248x; 1.0248x over previous
//
#include <hip/hip_runtime.h>
#include <hip/hip_bf16.h>

#define B_ 4
#define C_ 64
#define H_ 128
#define W_ 128
#define HW_ (H_ * W_)
#define OCH_ 18

typedef __attribute__((ext_vector_type(8))) short short8;
typedef __attribute__((ext_vector_type(16))) float f32x16;

// ws layout (bytes):
//   [0, 73728)                      w2b: main weights, A-frag order (bf16)
//   [73728, 110592)                 w2a: offset-conv weights, A-frag order (bf16)
//   [131072, 131072+2359296)        offsets buffer (fallback path only)
//   [2490368, 2490368+8388608)      xh : x in NHWC bf16, [b][h][w][c]
#define W2B_ELEMS (9 * 2 * 4 * 64 * 8)   // 36864
#define W2A_ELEMS (36 * 64 * 8)          // 18432
#define OFF_BYTE_OFS 131072
#define XH_BYTE_OFS  2490368
#define WS_NEED (XH_BYTE_OFS + (size_t)B_ * H_ * W_ * C_ * 2)

// LDS window: 4 chunk-planes (8ch each) x 5 rows x 128 cols x 16B, padded plane stride
#define PSTRIDE_B 10256                  // 5*128*16 + 16 pad (stride % 128B != 0)
#define WIN_BYTES (4 * PSTRIDE_B)        // 41024

__device__ __forceinline__ unsigned short f2bf(float f) {
  union { float f; unsigned u; } v; v.f = f;
  unsigned r = v.u + 0x7FFFu + ((v.u >> 16) & 1u);   // RNE
  return (unsigned short)(r >> 16);
}
__device__ __forceinline__ float bf2f(unsigned short h) {
  union { unsigned u; float f; } v; v.u = ((unsigned)h) << 16;
  return v.f;
}
__device__ __forceinline__ short f2bfh(float f) {     // hot path: HW cvt
  __hip_bfloat16 h = __float2bfloat16(f);
  return *reinterpret_cast<short*>(&h);
}
// bijective XCD swizzle for 512-block grids (512 % 8 == 0)
__device__ __forceinline__ int swz512(int x) { return (x & 7) * 64 + (x >> 3); }

// ---------------- weight pack (shared by both paths) ----------------
__device__ __forceinline__ void pack_weights_body(
    int idx, const float* __restrict__ wmain, const float* __restrict__ offw,
    unsigned short* __restrict__ ws_u) {
  if (idx < W2B_ELEMS) {
    int i = idx & 7, lane = (idx >> 3) & 63, s = (idx >> 9) & 3;
    int mq = (idx >> 11) & 1, t = idx >> 12;
    int o = mq * 32 + (lane & 31);
    int c = 16 * s + (lane >> 5) * 8 + i;
    ws_u[idx] = f2bf(wmain[(o * 64 + c) * 9 + t]);
  } else if (idx < W2B_ELEMS + W2A_ELEMS) {
    int j = idx - W2B_ELEMS;
    int i = j & 7, lane = (j >> 3) & 63, s = j >> 9;   // s 0..35
    int kg = 16 * s + (lane >> 5) * 8 + i;
    int t = kg >> 6, c = kg & 63, oc = lane & 31;
    ws_u[idx] = (oc < OCH_) ? f2bf(offw[(oc * 64 + c) * 9 + t]) : (unsigned short)0;
  }
}

// ---------------- prep kernel: NHWC repack (blocks 0..511) + weight pack (512+) ----------
__global__ __launch_bounds__(256) void prep_kernel(
    const float* __restrict__ x, const float* __restrict__ wmain,
    const float* __restrict__ offw, unsigned short* __restrict__ ws_u,
    unsigned short* __restrict__ xh) {
  const int tid = threadIdx.x;
  if (blockIdx.x < 512) {
    __shared__ float s[W_ * 65];
    const int h = blockIdx.x & (H_ - 1);
    const int b = blockIdx.x >> 7;
    const float* xb = x + ((size_t)b * C_ * H_ + h) * W_;
    // float4 loads: 8 per thread
    for (int i = tid; i < C_ * W_ / 4; i += 256) {
      int c = i >> 5, q = i & 31;
      float4 v = *reinterpret_cast<const float4*>(&xb[(size_t)c * HW_ + q * 4]);
      s[(q * 4 + 0) * 65 + c] = v.x;
      s[(q * 4 + 1) * 65 + c] = v.y;
      s[(q * 4 + 2) * 65 + c] = v.z;
      s[(q * 4 + 3) * 65 + c] = v.w;
    }
    __syncthreads();
    unsigned short* dst = xh + ((size_t)(b * H_ + h) * W_) * C_;
    for (int i = tid; i < W_ * 8; i += 256) {
      int w = i >> 3, g = i & 7;
      short8 v;
      #pragma unroll
      for (int j = 0; j < 8; ++j) v[j] = (short)f2bf(s[w * 65 + g * 8 + j]);
      *(short8*)&dst[w * C_ + g * 8] = v;
    }
  } else {
    pack_weights_body((blockIdx.x - 512) * 256 + tid, wmain, offw, ws_u);
  }
}

__global__ __launch_bounds__(256) void pack_w_only(
    const float* __restrict__ wmain, const float* __restrict__ offw,
    unsigned short* __restrict__ ws_u) {
  pack_weights_body(blockIdx.x * 256 + threadIdx.x, wmain, offw, ws_u);
}

// ---------------- per-tap deform+MFMA body (window gather, rare global fallback) ---------
template<int KI, int KJ, int CPH>
__device__ __forceinline__ void tap_body(
    float dy, float dx, int ho, int px, int lane, int b,
    const char* __restrict__ win, const unsigned short* __restrict__ xh,
    const unsigned short* __restrict__ wt2,   // w2b + tap*4096
    f32x16& acc0, f32x16& acc1) {
  const float ys = (float)(ho - 1 + KI) + dy;
  const float xs = (float)(px - 1 + KJ) + dx;
  const float y0f = floorf(ys), x0f = floorf(xs);
  const int y0 = (int)y0f, x0 = (int)x0f;
  const int y1 = y0 + 1, x1 = x0 + 1;
  const float wy1 = ys - y0f, wx1 = xs - x0f;
  const float wy0 = 1.f - wy1, wx0 = 1.f - wx1;
  const bool vy0 = (unsigned)y0 < (unsigned)H_, vy1 = (unsigned)y1 < (unsigned)H_;
  const bool vx0 = (unsigned)x0 < (unsigned)W_, vx1 = (unsigned)x1 < (unsigned)W_;
  const float g00 = (vy0 && vx0) ? wy0 * wx0 : 0.f;
  const float g01 = (vy0 && vx1) ? wy0 * wx1 : 0.f;
  const float g10 = (vy1 && vx0) ? wy1 * wx0 : 0.f;
  const float g11 = (vy1 && vx1) ? wy1 * wx1 : 0.f;
  const int yc0 = min(max(y0, 0), H_ - 1), yc1 = min(max(y1, 0), H_ - 1);
  const int xc0 = min(max(x0, 0), W_ - 1), xc1 = min(max(x1, 0), W_ - 1);
  const int rr0 = yc0 - ho + 2, rr1 = yc1 - ho + 2;
  const bool in0 = (unsigned)rr0 < 5u, in1 = (unsigned)rr1 < 5u;
  const int r0 = min(max(rr0, 0), 4), r1 = min(max(rr1, 0), 4);
  const int u00 = (r0 * 128 + xc0) << 4, u01 = (r0 * 128 + xc1) << 4;
  const int u10 = (r1 * 128 + xc0) << 4, u11 = (r1 * 128 + xc1) << 4;
  const int laneh = lane >> 5;
  #pragma unroll
  for (int ssl = 0; ssl < 2; ++ssl) {
    const int ss = CPH * 2 + ssl;
    const char* pb = win + (2 * ssl + laneh) * PSTRIDE_B;
    short8 c00 = *(const short8*)(pb + u00);
    short8 c01 = *(const short8*)(pb + u01);
    short8 c10 = *(const short8*)(pb + u10);
    short8 c11 = *(const short8*)(pb + u11);
    if (!in0 || !in1) {                         // rare (|dy| >= ~1)
      const int ch8 = (2 * ss + laneh) << 3;
      if (!in0) {
        c00 = *(const short8*)&xh[(((size_t)((b * H_ + yc0) * W_ + xc0)) << 6) + ch8];
        c01 = *(const short8*)&xh[(((size_t)((b * H_ + yc0) * W_ + xc1)) << 6) + ch8];
      }
      if (!in1) {
        c10 = *(const short8*)&xh[(((size_t)((b * H_ + yc1) * W_ + xc0)) << 6) + ch8];
        c11 = *(const short8*)&xh[(((size_t)((b * H_ + yc1) * W_ + xc1)) << 6) + ch8];
      }
    }
    short8 bf;
    #pragma unroll
    for (int i = 0; i < 8; ++i) {
      float v = g00 * bf2f((unsigned short)c00[i]) + g01 * bf2f((unsigned short)c01[i])
              + g10 * bf2f((unsigned short)c10[i]) + g11 * bf2f((unsigned short)c11[i]);
      bf[i] = f2bfh(v);
    }
    const short8 a0 = *(const short8*)&wt2[(ss * 64 + lane) * 8];
    const short8 a1 = *(const short8*)&wt2[((4 + ss) * 64 + lane) * 8];
    acc0 = __builtin_amdgcn_mfma_f32_32x32x16_bf16(a0, bf, acc0, 0, 0, 0);
    acc1 = __builtin_amdgcn_mfma_f32_32x32x16_bf16(a1, bf, acc1, 0, 0, 0);
  }
}

// ---- async stage: issue global loads into regs early, write to LDS late (T14) ----
#define STAGE_ISSUE(CPH)                                                                \
  _Pragma("unroll")                                                                     \
  for (int it = 0; it < 5; ++it) {                                                      \
    const int i = tid + it * 512;                                                       \
    const int p = i & 3;                                                                \
    const int j = i >> 2;                                                               \
    const int col = j & 127;                                                            \
    const int r = j >> 7;                                                               \
    const int srow = min(H_ - 1, max(0, ho - 2 + r));                                   \
    stg[it] = *(const short8*)&xh[(((size_t)((b * H_ + srow) * W_ + col)) << 6)         \
                                  + ((4 * (CPH) + p) << 3)];                            \
  }

#define STAGE_WRITE()                                                                   \
  _Pragma("unroll")                                                                     \
  for (int it = 0; it < 5; ++it) {                                                      \
    const int i = tid + it * 512;                                                       \
    const int p = i & 3;                                                                \
    const int j = i >> 2;                                                               \
    const int col = j & 127;                                                            \
    const int r = j >> 7;                                                               \
    *(short8*)(smem + p * PSTRIDE_B + ((r * 128 + col) << 4)) = stg[it];                \
  }

// offset-conv half: 18 K-steps with (s&3) in {2*CPH, 2*CPH+1}; dual acc chains
#define P1HALF(CPH)                                                                     \
  _Pragma("unroll")                                                                     \
  for (int t = 0; t < 9; ++t) {                                                         \
    _Pragma("unroll")                                                                   \
    for (int q = 0; q < 2; ++q) {                                                       \
      const int s = 4 * t + 2 * (CPH) + q;                                              \
      const int ki = t / 3, kj = t - 3 * (t / 3);                                       \
      const int row = ho - 1 + ki, col = px - 1 + kj;                                   \
      short8 bfr = {0, 0, 0, 0, 0, 0, 0, 0};                                            \
      if (((unsigned)row < (unsigned)H_) && ((unsigned)col < (unsigned)W_))             \
        bfr = *(const short8*)(smem + (2 * q + laneh) * PSTRIDE_B                       \
                               + (((ki + 1) * 128 + col) << 4));                        \
      const short8 afr = *(const short8*)&w2a[((size_t)s * 64 + lane) * 8];             \
      if (q == 0)                                                                       \
        pacc_a = __builtin_amdgcn_mfma_f32_32x32x16_bf16(afr, bfr, pacc_a, 0, 0, 0);    \
      else                                                                              \
        pacc_b = __builtin_amdgcn_mfma_f32_32x32x16_bf16(afr, bfr, pacc_b, 0, 0, 0);    \
    }                                                                                   \
  }

// extract dy/dx for tap T from pacc (C/D layout: row=oc=(reg&3)+8*(reg>>2)+4h, col=px)
#define EXT(T, J)                                                                       \
  {                                                                                     \
    constexpr int ocy = 2 * (T), ocx = 2 * (T) + 1;                                     \
    constexpr int ry = (ocy & 3) + 4 * (ocy >> 3), hy = (ocy >> 2) & 1;                 \
    constexpr int rx = (ocx & 3) + 4 * (ocx >> 3), hx = (ocx >> 2) & 1;                 \
    dys[J] = __shfl(pacc[ry], (lane & 31) + (hy << 5)) + ob[ocy];                       \
    dxs[J] = __shfl(pacc[rx], (lane & 31) + (hx << 5)) + ob[ocx];                       \
  }

#define TAP(KI, KJ, CPH, J)                                                             \
  tap_body<KI, KJ, CPH>(dys[J], dxs[J], ho, px, lane, b, smem, xh,                      \
                        w2b + ((KI) * 3 + (KJ)) * 4096, acc0, acc1)

#define P2CPH(CPH)                                                                      \
  if (sub == 0) {                                                                       \
    TAP(0, 0, CPH, 0); TAP(0, 1, CPH, 1); TAP(0, 2, CPH, 2); TAP(1, 0, CPH, 3);         \
  } else {                                                                              \
    TAP(1, 1, CPH, 0); TAP(1, 2, CPH, 1); TAP(2, 0, CPH, 2); TAP(2, 1, CPH, 3);         \
    TAP(2, 2, CPH, 4);                                                                  \
  }

// ---------------- fused kernel v4: round-6 structure + async-stage + dual pacc ----------
// block=(b,ho): 512 blocks x 512 threads (8 waves = 4 pairs x 2 subs).
__global__ __launch_bounds__(512, 4) void deform_fused4(
    const unsigned short* __restrict__ xh, const float* __restrict__ bias,
    const float* __restrict__ ob, const unsigned short* __restrict__ w2b,
    const unsigned short* __restrict__ w2a, float* __restrict__ out) {
  const int blk = swz512(blockIdx.x);
  const int ho = blk & (H_ - 1);
  const int b  = blk >> 7;
  const int tid = threadIdx.x;
  const int lane = tid & 63;
  const int wave = tid >> 6;
  const int pair = wave >> 1;
  const int sub  = wave & 1;
  const int px   = pair * 32 + (lane & 31);
  const int laneh = lane >> 5;

  __shared__ __align__(16) char smem[WIN_BYTES];   // 41 KB window; reused for reduction

  short8 stg[5];                        // async-stage register buffer (20 VGPR)

  // ================= phase 1: offset conv =================
  f32x16 pacc_a, pacc_b;
  #pragma unroll
  for (int r = 0; r < 16; ++r) { pacc_a[r] = 0.f; pacc_b[r] = 0.f; }

  STAGE_ISSUE(0);
  STAGE_WRITE();                        // exposed (kernel start; nothing to hide under)
  __syncthreads();

  STAGE_ISSUE(1);                       // CPH1 loads fly during P1HALF(0)
  P1HALF(0);
  __syncthreads();                      // all CPH0 window reads complete
  STAGE_WRITE();                        // barrier-drain already waited vmcnt
  __syncthreads();

  STAGE_ISSUE(0);                       // CPH0 reload flies during P1HALF(1)+P2CPH(1)
  P1HALF(1);

  f32x16 pacc;
  #pragma unroll
  for (int r = 0; r < 16; ++r) pacc[r] = pacc_a[r] + pacc_b[r];

  // offsets for this wave's taps, wave-internal via shfl
  float dys[5], dxs[5];
  if (sub == 0) {
    EXT(0, 0); EXT(1, 1); EXT(2, 2); EXT(3, 3);
    dys[4] = 0.f; dxs[4] = 0.f;
  } else {
    EXT(4, 0); EXT(5, 1); EXT(6, 2); EXT(7, 3); EXT(8, 4);
  }

  // ================= phase 2: deformable sample + einsum =================
  f32x16 acc0, acc1;
  #pragma unroll
  for (int r = 0; r < 16; ++r) { acc0[r] = 0.f; acc1[r] = 0.f; }

  P2CPH(1);                 // window holds channels 32..63
  __syncthreads();          // all CPH1 reads complete
  STAGE_WRITE();
  __syncthreads();
  P2CPH(0);                 // channels 0..31
  __syncthreads();

  // ---- pairwise (sub) reduction in reused window LDS + epilogue ----
  float* red = (float*)smem;
  if (sub) {
    #pragma unroll
    for (int i = 0; i < 16; ++i) {
      red[(i * 4 + pair) * 64 + lane]        = acc0[i];
      red[((16 + i) * 4 + pair) * 64 + lane] = acc1[i];
    }
  }
  __syncthreads();
  if (!sub) {
    #pragma unroll
    for (int i = 0; i < 16; ++i) {
      acc0[i] += red[(i * 4 + pair) * 64 + lane];
      acc1[i] += red[((16 + i) * 4 + pair) * 64 + lane];
    }
    #pragma unroll
    for (int reg = 0; reg < 16; ++reg) {
      int row = (reg & 3) + 8 * (reg >> 2) + 4 * laneh;
      out[((b * 64 + row)      * H_ + ho) * W_ + px] = acc0[reg] + bias[row];
      out[((b * 64 + 32 + row) * H_ + ho) * W_ + px] = acc1[reg] + bias[32 + row];
    }
  }
}

// ================= fallback path (round-3 CHW, used only if ws too small) =================
__global__ __launch_bounds__(256) void offset_conv_mfma(
    const float* __restrict__ x, const float* __restrict__ ob,
    const unsigned short* __restrict__ w2a, unsigned short* __restrict__ offout) {
  const int ho = blockIdx.x & (H_ - 1);
  const int b  = blockIdx.x >> 7;
  const int tid = threadIdx.x;
  const int lane = tid & 63;
  const int wv = tid >> 6;
  __shared__ __align__(16) unsigned short sx[3 * 130 * 64];
  const float* xb = x + (size_t)b * C_ * HW_;
  for (int i = tid; i < 96 * 130; i += 256) {
    int col = i % 130;
    int c2  = i / 130;
    int r   = c2 >> 5;
    int c   = (c2 & 31) * 2;
    int row = ho - 1 + r, gcol = col - 1;
    float v0 = 0.f, v1 = 0.f;
    if ((unsigned)row < (unsigned)H_ && (unsigned)gcol < (unsigned)W_) {
      v0 = xb[(size_t)c * HW_ + row * W_ + gcol];
      v1 = xb[(size_t)(c + 1) * HW_ + row * W_ + gcol];
    }
    unsigned pk = (unsigned)f2bf(v0) | ((unsigned)f2bf(v1) << 16);
    int cblk = (c >> 3) ^ (col & 7);
    int h = ((r * 130 + col) * 8 + cblk) * 8 + (c & 7);
    *(unsigned*)&sx[h] = pk;
  }
  __syncthreads();
  const int px  = wv * 32 + (lane & 31);
  const int cbh = lane >> 5;
  f32x16 acc;
  #pragma unroll
  for (int r = 0; r < 16; ++r) acc[r] = 0.f;
  for (int s = 0; s < 36; ++s) {
    int t  = s >> 2;
    int ki = t / 3, kj = t - 3 * ki;
    int j  = px + kj;
    int cblk = (s & 3) * 2 + cbh;
    const short8 bfr = *(const short8*)&sx[((ki * 130 + j) * 8 + (cblk ^ (j & 7))) * 8];
    const short8 afr = *(const short8*)&w2a[(s * 64 + lane) * 8];
    acc = __builtin_amdgcn_mfma_f32_32x32x16_bf16(afr, bfr, acc, 0, 0, 0);
  }
  #pragma unroll
  for (int reg = 0; reg < 16; ++reg) {
    int oc = (reg & 3) + 8 * (reg >> 2) + 4 * (lane >> 5);
    if (oc < OCH_) {
      float v = acc[reg] + ob[oc];
      offout[((b * OCH_ + oc) * H_ + ho) * W_ + px] = f2bf(v);
    }
  }
}

__global__ __launch_bounds__(256) void deform_mfma(
    const float* __restrict__ x, const float* __restrict__ bias,
    const unsigned short* __restrict__ w2b, const unsigned short* __restrict__ offb,
    float* __restrict__ out) {
  const int ho = blockIdx.x & (H_ - 1);
  const int b  = blockIdx.x >> 7;
  const int lane = threadIdx.x & 63;
  const int wv   = threadIdx.x >> 6;
  const int px   = wv * 32 + (lane & 31);
  const int cb   = (lane >> 5) * 8;
  const float* xb = x + (size_t)b * C_ * HW_;
  f32x16 acc0, acc1;
  #pragma unroll
  for (int r = 0; r < 16; ++r) { acc0[r] = 0.f; acc1[r] = 0.f; }
  for (int t = 0; t < 9; ++t) {
    const int ki = t / 3, kj = t - 3 * ki;
    float dy = bf2f(offb[((b * OCH_ + 2 * t)     * H_ + ho) * W_ + px]);
    float dx = bf2f(offb[((b * OCH_ + 2 * t + 1) * H_ + ho) * W_ + px]);
    float ys = (float)(ho - 1 + ki) + dy;
    float xs = (float)(px - 1 + kj) + dx;
    float y0f = floorf(ys), x0f = floorf(xs);
    int y0 = (int)y0f, x0 = (int)x0f;
    int y1 = y0 + 1,   x1 = x0 + 1;
    float wy1 = ys - y0f, wx1 = xs - x0f;
    float wy0 = 1.f - wy1, wx0 = 1.f - wx1;
    bool vy0 = (unsigned)y0 < (unsigned)H_, vy1 = (unsigned)y1 < (unsigned)H_;
    bool vx0 = (unsigned)x0 < (unsigned)W_, vx1 = (unsigned)x1 < (unsigned)W_;
    int yc0 = min(max(y0, 0), H_ - 1), yc1 = min(max(y1, 0), H_ - 1);
    int xc0 = min(max(x0, 0), W_ - 1), xc1 = min(max(x1, 0), W_ - 1);
    const int o00 = yc0 * W_ + xc0, o01 = yc0 * W_ + xc1;
    const int o10 = yc1 * W_ + xc0, o11 = yc1 * W_ + xc1;
    const float g00 = (vy0 && vx0) ? wy0 * wx0 : 0.f;
    const float g01 = (vy0 && vx1) ? wy0 * wx1 : 0.f;
    const float g10 = (vy1 && vx0) ? wy1 * wx0 : 0.f;
    const float g11 = (vy1 && vx1) ? wy1 * wx1 : 0.f;
    const short8* wp = (const short8*)(w2b + (size_t)t * 2 * 4 * 64 * 8);
    short8 a0[4], a1[4];
    #pragma unroll
    for (int s = 0; s < 4; ++s) {
      a0[s] = wp[s * 64 + lane];
      a1[s] = wp[(4 + s) * 64 + lane];
    }
    #pragma unroll
    for (int s = 0; s < 4; ++s) {
      const int cidx = (cb + 16 * s) * HW_;
      short8 bf;
      #pragma unroll
      for (int i = 0; i < 8; ++i) {
        const int bi = cidx + i * HW_;
        float v = g00 * xb[bi + o00] + g01 * xb[bi + o01]
                + g10 * xb[bi + o10] + g11 * xb[bi + o11];
        bf[i] = (short)f2bf(v);
      }
      acc0 = __builtin_amdgcn_mfma_f32_32x32x16_bf16(a0[s], bf, acc0, 0, 0, 0);
      acc1 = __builtin_amdgcn_mfma_f32_32x32x16_bf16(a1[s], bf, acc1, 0, 0, 0);
    }
  }
  #pragma unroll
  for (int reg = 0; reg < 16; ++reg) {
    int row = (reg & 3) + 8 * (reg >> 2) + 4 * (lane >> 5);
    out[((b * 64 + row)      * H_ + ho) * W_ + px] = acc0[reg] + bias[row];
    out[((b * 64 + 32 + row) * H_ + ho) * W_ + px] = acc1[reg] + bias[32 + row];
  }
}

extern "C" void kernel_launch(void* const* d_in, const int* in_sizes, int n_in,
                              void* d_out, int out_size, void* d_ws, size_t ws_size,
                              hipStream_t stream) {
  const float* x    = (const float*)d_in[0];
  const float* wt   = (const float*)d_in[1];
  const float* bias = (const float*)d_in[2];
  const float* ow   = (const float*)d_in[3];
  const float* ob   = (const float*)d_in[4];
  float* out = (float*)d_out;

  unsigned short* ws_u  = (unsigned short*)d_ws;
  unsigned short* w2b   = ws_u;
  unsigned short* w2a   = ws_u + W2B_ELEMS;
  unsigned short* offbf = (unsigned short*)((char*)d_ws + OFF_BYTE_OFS);
  unsigned short* xh    = (unsigned short*)((char*)d_ws + XH_BYTE_OFS);

  const int pack_blocks = (W2B_ELEMS + W2A_ELEMS + 255) / 256;   // 216

  if (ws_size >= WS_NEED) {
    prep_kernel<<<512 + pack_blocks, 256, 0, stream>>>(x, wt, ow, ws_u, xh);
    deform_fused4<<<512, 512, 0, stream>>>(xh, bias, ob, w2b, w2a, out);
  } else {
    pack_w_only<<<pack_blocks, 256, 0, stream>>>(wt, ow, ws_u);
    offset_conv_mfma<<<B_ * H_, 256, 0, stream>>>(x, ob, w2a, offbf);
    deform_mfma<<<B_ * H_, 256, 0, stream>>>(x, bias, w2b, offbf, out);
  }
}

// Round 9
// 42.427 us; speedup vs baseline: 1.0827x; 1.0565x over previous
//
#include <hip/hip_runtime.h>
#include <hip/hip_bf16.h>

#define B_ 4
#define C_ 64
#define H_ 128
#define W_ 128
#define HW_ (H_ * W_)
#define OCH_ 18

typedef __attribute__((ext_vector_type(8))) short short8;
typedef __attribute__((ext_vector_type(16))) float f32x16;

// ws layout (bytes):
//   [0, 73728)                      w2b: main weights, A-frag order (bf16)
//   [73728, 110592)                 w2a: offset-conv weights, A-frag order (bf16)
//   [131072, 131072+2359296)        offsets buffer (fallback path only)
//   [2490368, 2490368+8388608)      xh : x in NHWC bf16, [b][h][w][c]
#define W2B_ELEMS (9 * 2 * 4 * 64 * 8)   // 36864
#define W2A_ELEMS (36 * 64 * 8)          // 18432
#define OFF_BYTE_OFS 131072
#define XH_BYTE_OFS  2490368
#define WS_NEED (XH_BYTE_OFS + (size_t)B_ * H_ * W_ * C_ * 2)

// LDS: 8 chunk-planes (8ch each) x 5 rows x 128 cols x 16B, padded plane stride,
// then P1-partial exchange region.
#define PSTRIDE_B 10256                  // 5*128*16 + 16 pad (stride % 128B != 0)
#define WIN_BYTES (8 * PSTRIDE_B)        // 82048
#define PART_OFS  WIN_BYTES              // float part[pair][sub][18][32] = 18432 B
#define SMEM_BYTES (WIN_BYTES + 2 * 4 * 18 * 32 * 4)   // 100480

__device__ __forceinline__ unsigned short f2bf(float f) {
  union { float f; unsigned u; } v; v.f = f;
  unsigned r = v.u + 0x7FFFu + ((v.u >> 16) & 1u);   // RNE
  return (unsigned short)(r >> 16);
}
__device__ __forceinline__ float bf2f(unsigned short h) {
  union { unsigned u; float f; } v; v.u = ((unsigned)h) << 16;
  return v.f;
}
__device__ __forceinline__ short f2bfh(float f) {     // hot path: HW cvt
  __hip_bfloat16 h = __float2bfloat16(f);
  return *reinterpret_cast<short*>(&h);
}
// bijective XCD swizzle for 512-block grids (512 % 8 == 0)
__device__ __forceinline__ int swz512(int x) { return (x & 7) * 64 + (x >> 3); }

// ---------------- weight pack (shared by both paths) ----------------
__device__ __forceinline__ void pack_weights_body(
    int idx, const float* __restrict__ wmain, const float* __restrict__ offw,
    unsigned short* __restrict__ ws_u) {
  if (idx < W2B_ELEMS) {
    int i = idx & 7, lane = (idx >> 3) & 63, s = (idx >> 9) & 3;
    int mq = (idx >> 11) & 1, t = idx >> 12;
    int o = mq * 32 + (lane & 31);
    int c = 16 * s + (lane >> 5) * 8 + i;
    ws_u[idx] = f2bf(wmain[(o * 64 + c) * 9 + t]);
  } else if (idx < W2B_ELEMS + W2A_ELEMS) {
    int j = idx - W2B_ELEMS;
    int i = j & 7, lane = (j >> 3) & 63, s = j >> 9;   // s 0..35
    int kg = 16 * s + (lane >> 5) * 8 + i;
    int t = kg >> 6, c = kg & 63, oc = lane & 31;
    ws_u[idx] = (oc < OCH_) ? f2bf(offw[(oc * 64 + c) * 9 + t]) : (unsigned short)0;
  }
}

// ---------------- prep kernel: NHWC repack (blocks 0..511) + weight pack (512+) ----------
__global__ __launch_bounds__(256) void prep_kernel(
    const float* __restrict__ x, const float* __restrict__ wmain,
    const float* __restrict__ offw, unsigned short* __restrict__ ws_u,
    unsigned short* __restrict__ xh) {
  const int tid = threadIdx.x;
  if (blockIdx.x < 512) {
    __shared__ float s[W_ * 65];
    const int h = blockIdx.x & (H_ - 1);
    const int b = blockIdx.x >> 7;
    const float* xb = x + ((size_t)b * C_ * H_ + h) * W_;
    for (int i = tid; i < C_ * W_ / 4; i += 256) {
      int c = i >> 5, q = i & 31;
      float4 v = *reinterpret_cast<const float4*>(&xb[(size_t)c * HW_ + q * 4]);
      s[(q * 4 + 0) * 65 + c] = v.x;
      s[(q * 4 + 1) * 65 + c] = v.y;
      s[(q * 4 + 2) * 65 + c] = v.z;
      s[(q * 4 + 3) * 65 + c] = v.w;
    }
    __syncthreads();
    unsigned short* dst = xh + ((size_t)(b * H_ + h) * W_) * C_;
    for (int i = tid; i < W_ * 8; i += 256) {
      int w = i >> 3, g = i & 7;
      short8 v;
      #pragma unroll
      for (int j = 0; j < 8; ++j) v[j] = (short)f2bf(s[w * 65 + g * 8 + j]);
      *(short8*)&dst[w * C_ + g * 8] = v;
    }
  } else {
    pack_weights_body((blockIdx.x - 512) * 256 + tid, wmain, offw, ws_u);
  }
}

__global__ __launch_bounds__(256) void pack_w_only(
    const float* __restrict__ wmain, const float* __restrict__ offw,
    unsigned short* __restrict__ ws_u) {
  pack_weights_body(blockIdx.x * 256 + threadIdx.x, wmain, offw, ws_u);
}

// ---------------- full-K per-tap body: coords once, 4 K-slices, window gathers ----------
template<int KI, int KJ>
__device__ __forceinline__ void tap_full(
    float dy, float dx, int ho, int px, int lane, int b,
    const char* __restrict__ win, const unsigned short* __restrict__ xh,
    const unsigned short* __restrict__ wt2,   // w2b + tap*4096
    f32x16& acc0, f32x16& acc1) {
  const float ys = (float)(ho - 1 + KI) + dy;
  const float xs = (float)(px - 1 + KJ) + dx;
  const float y0f = floorf(ys), x0f = floorf(xs);
  const int y0 = (int)y0f, x0 = (int)x0f;
  const int y1 = y0 + 1, x1 = x0 + 1;
  const float wy1 = ys - y0f, wx1 = xs - x0f;
  const float wy0 = 1.f - wy1, wx0 = 1.f - wx1;
  const bool vy0 = (unsigned)y0 < (unsigned)H_, vy1 = (unsigned)y1 < (unsigned)H_;
  const bool vx0 = (unsigned)x0 < (unsigned)W_, vx1 = (unsigned)x1 < (unsigned)W_;
  const float g00 = (vy0 && vx0) ? wy0 * wx0 : 0.f;
  const float g01 = (vy0 && vx1) ? wy0 * wx1 : 0.f;
  const float g10 = (vy1 && vx0) ? wy1 * wx0 : 0.f;
  const float g11 = (vy1 && vx1) ? wy1 * wx1 : 0.f;
  const int yc0 = min(max(y0, 0), H_ - 1), yc1 = min(max(y1, 0), H_ - 1);
  const int xc0 = min(max(x0, 0), W_ - 1), xc1 = min(max(x1, 0), W_ - 1);
  const int rr0 = yc0 - ho + 2, rr1 = yc1 - ho + 2;
  const bool in0 = (unsigned)rr0 < 5u, in1 = (unsigned)rr1 < 5u;
  const int r0 = min(max(rr0, 0), 4), r1 = min(max(rr1, 0), 4);
  const int u00 = (r0 * 128 + xc0) << 4, u01 = (r0 * 128 + xc1) << 4;
  const int u10 = (r1 * 128 + xc0) << 4, u11 = (r1 * 128 + xc1) << 4;
  const int laneh = lane >> 5;
  #pragma unroll
  for (int ss = 0; ss < 4; ++ss) {
    const char* pb = win + (2 * ss + laneh) * PSTRIDE_B;
    short8 c00 = *(const short8*)(pb + u00);
    short8 c01 = *(const short8*)(pb + u01);
    short8 c10 = *(const short8*)(pb + u10);
    short8 c11 = *(const short8*)(pb + u11);
    if (!in0 || !in1) {                         // rare (|dy| >= ~1)
      const int ch8 = (2 * ss + laneh) << 3;
      if (!in0) {
        c00 = *(const short8*)&xh[(((size_t)((b * H_ + yc0) * W_ + xc0)) << 6) + ch8];
        c01 = *(const short8*)&xh[(((size_t)((b * H_ + yc0) * W_ + xc1)) << 6) + ch8];
      }
      if (!in1) {
        c10 = *(const short8*)&xh[(((size_t)((b * H_ + yc1) * W_ + xc0)) << 6) + ch8];
        c11 = *(const short8*)&xh[(((size_t)((b * H_ + yc1) * W_ + xc1)) << 6) + ch8];
      }
    }
    short8 bf;
    #pragma unroll
    for (int i = 0; i < 8; ++i) {
      float v = g00 * bf2f((unsigned short)c00[i]) + g01 * bf2f((unsigned short)c01[i])
              + g10 * bf2f((unsigned short)c10[i]) + g11 * bf2f((unsigned short)c11[i]);
      bf[i] = f2bfh(v);
    }
    const short8 a0 = *(const short8*)&wt2[(ss * 64 + lane) * 8];
    const short8 a1 = *(const short8*)&wt2[((4 + ss) * 64 + lane) * 8];
    acc0 = __builtin_amdgcn_mfma_f32_32x32x16_bf16(a0, bf, acc0, 0, 0, 0);
    acc1 = __builtin_amdgcn_mfma_f32_32x32x16_bf16(a1, bf, acc1, 0, 0, 0);
  }
}

#define TAP(KI, KJ, J)                                                                  \
  tap_full<KI, KJ>(dys[J], dxs[J], ho, px, lane, b, smem, xh,                           \
                   w2b + ((KI) * 3 + (KJ)) * 4096, acc0, acc1)

// ---------------- fused kernel v5: full-C window, 1 stage, 4 barriers ----------------
// block=(b,ho): 512 blocks x 512 threads (8 waves = 4 pairs x 2 subs), 1 block/CU.
// stage all 64ch once -> P1 sub-split (18 K-steps/wave) -> LDS partial exchange ->
// P2 tap-split, per-tap params once, all 4 K-slices in one region.
__global__ __launch_bounds__(512, 2) void deform_fused5(
    const unsigned short* __restrict__ xh, const float* __restrict__ bias,
    const float* __restrict__ ob, const unsigned short* __restrict__ w2b,
    const unsigned short* __restrict__ w2a, float* __restrict__ out) {
  const int blk = swz512(blockIdx.x);
  const int ho = blk & (H_ - 1);
  const int b  = blk >> 7;
  const int tid = threadIdx.x;
  const int lane = tid & 63;
  const int wave = tid >> 6;
  const int pair = wave >> 1;
  const int sub  = wave & 1;
  const int px   = pair * 32 + (lane & 31);
  const int pxl  = lane & 31;
  const int laneh = lane >> 5;

  __shared__ __align__(16) char smem[SMEM_BYTES];   // 98.1 KB: window + P1 partials

  // ================= stage: all 8 planes, rows ho-2..ho+2 (clamped) =================
  short8 stg[10];
  #pragma unroll
  for (int it = 0; it < 10; ++it) {
    const int i = tid + it * 512;
    const int p = i & 7;
    const int col = (i >> 3) & 127;
    const int r = i >> 10;
    const int srow = min(H_ - 1, max(0, ho - 2 + r));
    stg[it] = *(const short8*)&xh[(((size_t)((b * H_ + srow) * W_ + col)) << 6) + (p << 3)];
  }
  #pragma unroll
  for (int it = 0; it < 10; ++it) {
    const int i = tid + it * 512;
    const int p = i & 7;
    const int col = (i >> 3) & 127;
    const int r = i >> 10;
    *(short8*)(smem + p * PSTRIDE_B + ((r * 128 + col) << 4)) = stg[it];
  }
  __syncthreads();

  // ================= phase 1: offset conv, K split across subs =================
  f32x16 pacc_a, pacc_b;
  #pragma unroll
  for (int r = 0; r < 16; ++r) { pacc_a[r] = 0.f; pacc_b[r] = 0.f; }

  const int s0 = sub * 18;
  #pragma unroll
  for (int q = 0; q < 18; ++q) {
    const int s  = s0 + q;
    const int t  = s >> 2;
    const int ki = t / 3, kj = t - 3 * (t / 3);
    const int row = ho - 1 + ki;
    const int col = px - 1 + kj;
    short8 bfr = {0, 0, 0, 0, 0, 0, 0, 0};
    if (((unsigned)row < (unsigned)H_) && ((unsigned)col < (unsigned)W_))
      bfr = *(const short8*)(smem + ((s & 3) * 2 + laneh) * PSTRIDE_B
                             + (((ki + 1) * 128 + col) << 4));
    const short8 afr = *(const short8*)&w2a[((size_t)s * 64 + lane) * 8];
    if (q & 1)
      pacc_b = __builtin_amdgcn_mfma_f32_32x32x16_bf16(afr, bfr, pacc_b, 0, 0, 0);
    else
      pacc_a = __builtin_amdgcn_mfma_f32_32x32x16_bf16(afr, bfr, pacc_a, 0, 0, 0);
  }

  // write P1 partials (oc rows < 18) to exchange region
  {
    float* part = (float*)(smem + PART_OFS);
    #pragma unroll
    for (int reg = 0; reg < 16; ++reg) {
      const int oc = (reg & 3) + 8 * (reg >> 2) + 4 * laneh;
      if (oc < OCH_)
        part[(((pair << 1) + sub) * OCH_ + oc) * 32 + pxl] = pacc_a[reg] + pacc_b[reg];
    }
  }
  __syncthreads();

  // read offsets for this wave's taps (sum both subs' partials + offset bias)
  const int t0 = sub * 4;               // sub0: taps 0..3, sub1: taps 4..8
  const int nt = 4 + sub;
  float dys[5], dxs[5];
  {
    const float* part = (const float*)(smem + PART_OFS);
    const int base0 = ((pair << 1) + 0) * OCH_ * 32 + pxl;
    const int base1 = ((pair << 1) + 1) * OCH_ * 32 + pxl;
    #pragma unroll
    for (int j = 0; j < 5; ++j) {
      int tt = t0 + ((j < nt) ? j : 0);
      int ocy = 2 * tt, ocx = 2 * tt + 1;
      dys[j] = part[base0 + ocy * 32] + part[base1 + ocy * 32] + ob[ocy];
      dxs[j] = part[base0 + ocx * 32] + part[base1 + ocx * 32] + ob[ocx];
    }
  }

  // ================= phase 2: deformable sample + einsum (tap-split) =================
  f32x16 acc0, acc1;
  #pragma unroll
  for (int r = 0; r < 16; ++r) { acc0[r] = 0.f; acc1[r] = 0.f; }

  if (sub == 0) {
    TAP(0, 0, 0); TAP(0, 1, 1); TAP(0, 2, 2); TAP(1, 0, 3);
  } else {
    TAP(1, 1, 0); TAP(1, 2, 1); TAP(2, 0, 2); TAP(2, 1, 3); TAP(2, 2, 4);
  }
  __syncthreads();                      // window reads complete; reuse as reduction

  // ---- pairwise (sub) reduction + epilogue ----
  float* red = (float*)smem;
  if (sub) {
    #pragma unroll
    for (int i = 0; i < 16; ++i) {
      red[(i * 4 + pair) * 64 + lane]        = acc0[i];
      red[((16 + i) * 4 + pair) * 64 + lane] = acc1[i];
    }
  }
  __syncthreads();
  if (!sub) {
    #pragma unroll
    for (int i = 0; i < 16; ++i) {
      acc0[i] += red[(i * 4 + pair) * 64 + lane];
      acc1[i] += red[((16 + i) * 4 + pair) * 64 + lane];
    }
    #pragma unroll
    for (int reg = 0; reg < 16; ++reg) {
      int row = (reg & 3) + 8 * (reg >> 2) + 4 * laneh;
      out[((b * 64 + row)      * H_ + ho) * W_ + px] = acc0[reg] + bias[row];
      out[((b * 64 + 32 + row) * H_ + ho) * W_ + px] = acc1[reg] + bias[32 + row];
    }
  }
}

// ================= fallback path (round-3 CHW, used only if ws too small) =================
__global__ __launch_bounds__(256) void offset_conv_mfma(
    const float* __restrict__ x, const float* __restrict__ ob,
    const unsigned short* __restrict__ w2a, unsigned short* __restrict__ offout) {
  const int ho = blockIdx.x & (H_ - 1);
  const int b  = blockIdx.x >> 7;
  const int tid = threadIdx.x;
  const int lane = tid & 63;
  const int wv = tid >> 6;
  __shared__ __align__(16) unsigned short sx[3 * 130 * 64];
  const float* xb = x + (size_t)b * C_ * HW_;
  for (int i = tid; i < 96 * 130; i += 256) {
    int col = i % 130;
    int c2  = i / 130;
    int r   = c2 >> 5;
    int c   = (c2 & 31) * 2;
    int row = ho - 1 + r, gcol = col - 1;
    float v0 = 0.f, v1 = 0.f;
    if ((unsigned)row < (unsigned)H_ && (unsigned)gcol < (unsigned)W_) {
      v0 = xb[(size_t)c * HW_ + row * W_ + gcol];
      v1 = xb[(size_t)(c + 1) * HW_ + row * W_ + gcol];
    }
    unsigned pk = (unsigned)f2bf(v0) | ((unsigned)f2bf(v1) << 16);
    int cblk = (c >> 3) ^ (col & 7);
    int h = ((r * 130 + col) * 8 + cblk) * 8 + (c & 7);
    *(unsigned*)&sx[h] = pk;
  }
  __syncthreads();
  const int px  = wv * 32 + (lane & 31);
  const int cbh = lane >> 5;
  f32x16 acc;
  #pragma unroll
  for (int r = 0; r < 16; ++r) acc[r] = 0.f;
  for (int s = 0; s < 36; ++s) {
    int t  = s >> 2;
    int ki = t / 3, kj = t - 3 * ki;
    int j  = px + kj;
    int cblk = (s & 3) * 2 + cbh;
    const short8 bfr = *(const short8*)&sx[((ki * 130 + j) * 8 + (cblk ^ (j & 7))) * 8];
    const short8 afr = *(const short8*)&w2a[(s * 64 + lane) * 8];
    acc = __builtin_amdgcn_mfma_f32_32x32x16_bf16(afr, bfr, acc, 0, 0, 0);
  }
  #pragma unroll
  for (int reg = 0; reg < 16; ++reg) {
    int oc = (reg & 3) + 8 * (reg >> 2) + 4 * (lane >> 5);
    if (oc < OCH_) {
      float v = acc[reg] + ob[oc];
      offout[((b * OCH_ + oc) * H_ + ho) * W_ + px] = f2bf(v);
    }
  }
}

__global__ __launch_bounds__(256) void deform_mfma(
    const float* __restrict__ x, const float* __restrict__ bias,
    const unsigned short* __restrict__ w2b, const unsigned short* __restrict__ offb,
    float* __restrict__ out) {
  const int ho = blockIdx.x & (H_ - 1);
  const int b  = blockIdx.x >> 7;
  const int lane = threadIdx.x & 63;
  const int wv   = threadIdx.x >> 6;
  const int px   = wv * 32 + (lane & 31);
  const int cb   = (lane >> 5) * 8;
  const float* xb = x + (size_t)b * C_ * HW_;
  f32x16 acc0, acc1;
  #pragma unroll
  for (int r = 0; r < 16; ++r) { acc0[r] = 0.f; acc1[r] = 0.f; }
  for (int t = 0; t < 9; ++t) {
    const int ki = t / 3, kj = t - 3 * ki;
    float dy = bf2f(offb[((b * OCH_ + 2 * t)     * H_ + ho) * W_ + px]);
    float dx = bf2f(offb[((b * OCH_ + 2 * t + 1) * H_ + ho) * W_ + px]);
    float ys = (float)(ho - 1 + ki) + dy;
    float xs = (float)(px - 1 + kj) + dx;
    float y0f = floorf(ys), x0f = floorf(xs);
    int y0 = (int)y0f, x0 = (int)x0f;
    int y1 = y0 + 1,   x1 = x0 + 1;
    float wy1 = ys - y0f, wx1 = xs - x0f;
    float wy0 = 1.f - wy1, wx0 = 1.f - wx1;
    bool vy0 = (unsigned)y0 < (unsigned)H_, vy1 = (unsigned)y1 < (unsigned)H_;
    bool vx0 = (unsigned)x0 < (unsigned)W_, vx1 = (unsigned)x1 < (unsigned)W_;
    int yc0 = min(max(y0, 0), H_ - 1), yc1 = min(max(y1, 0), H_ - 1);
    int xc0 = min(max(x0, 0), W_ - 1), xc1 = min(max(x1, 0), W_ - 1);
    const int o00 = yc0 * W_ + xc0, o01 = yc0 * W_ + xc1;
    const int o10 = yc1 * W_ + xc0, o11 = yc1 * W_ + xc1;
    const float g00 = (vy0 && vx0) ? wy0 * wx0 : 0.f;
    const float g01 = (vy0 && vx1) ? wy0 * wx1 : 0.f;
    const float g10 = (vy1 && vx0) ? wy1 * wx0 : 0.f;
    const float g11 = (vy1 && vx1) ? wy1 * wx1 : 0.f;
    const short8* wp = (const short8*)(w2b + (size_t)t * 2 * 4 * 64 * 8);
    short8 a0[4], a1[4];
    #pragma unroll
    for (int s = 0; s < 4; ++s) {
      a0[s] = wp[s * 64 + lane];
      a1[s] = wp[(4 + s) * 64 + lane];
    }
    #pragma unroll
    for (int s = 0; s < 4; ++s) {
      const int cidx = (cb + 16 * s) * HW_;
      short8 bf;
      #pragma unroll
      for (int i = 0; i < 8; ++i) {
        const int bi = cidx + i * HW_;
        float v = g00 * xb[bi + o00] + g01 * xb[bi + o01]
                + g10 * xb[bi + o10] + g11 * xb[bi + o11];
        bf[i] = (short)f2bf(v);
      }
      acc0 = __builtin_amdgcn_mfma_f32_32x32x16_bf16(a0[s], bf, acc0, 0, 0, 0);
      acc1 = __builtin_amdgcn_mfma_f32_32x32x16_bf16(a1[s], bf, acc1, 0, 0, 0);
    }
  }
  #pragma unroll
  for (int reg = 0; reg < 16; ++reg) {
    int row = (reg & 3) + 8 * (reg >> 2) + 4 * (lane >> 5);
    out[((b * 64 + row)      * H_ + ho) * W_ + px] = acc0[reg] + bias[row];
    out[((b * 64 + 32 + row) * H_ + ho) * W_ + px] = acc1[reg] + bias[32 + row];
  }
}

extern "C" void kernel_launch(void* const* d_in, const int* in_sizes, int n_in,
                              void* d_out, int out_size, void* d_ws, size_t ws_size,
                              hipStream_t stream) {
  const float* x    = (const float*)d_in[0];
  const float* wt   = (const float*)d_in[1];
  const float* bias = (const float*)d_in[2];
  const float* ow   = (const float*)d_in[3];
  const float* ob   = (const float*)d_in[4];
  float* out = (float*)d_out;

  unsigned short* ws_u  = (unsigned short*)d_ws;
  unsigned short* w2b   = ws_u;
  unsigned short* w2a   = ws_u + W2B_ELEMS;
  unsigned short* offbf = (unsigned short*)((char*)d_ws + OFF_BYTE_OFS);
  unsigned short* xh    = (unsigned short*)((char*)d_ws + XH_BYTE_OFS);

  const int pack_blocks = (W2B_ELEMS + W2A_ELEMS + 255) / 256;   // 216

  if (ws_size >= WS_NEED) {
    prep_kernel<<<512 + pack_blocks, 256, 0, stream>>>(x, wt, ow, ws_u, xh);
    deform_fused5<<<512, 512, 0, stream>>>(xh, bias, ob, w2b, w2a, out);
  } else {
    pack_w_only<<<pack_blocks, 256, 0, stream>>>(wt, ow, ws_u);
    offset_conv_mfma<<<B_ * H_, 256, 0, stream>>>(x, ob, w2a, offbf);
    deform_mfma<<<B_ * H_, 256, 0, stream>>>(x, bias, w2b, offbf, out);
  }
}

// Round 10
// 40.472 us; speedup vs baseline: 1.1350x; 1.0483x over previous
//
#include <hip/hip_runtime.h>
#include <hip/hip_bf16.h>

#define B_ 4
#define C_ 64
#define H_ 128
#define W_ 128
#define HW_ (H_ * W_)
#define OCH_ 18

typedef __attribute__((ext_vector_type(8))) short short8;
typedef __attribute__((ext_vector_type(16))) float f32x16;

// ws layout (elements of unsigned short):
//   [0, W2B_ELEMS)              w2b: main weights, A-frag order (bf16)
//   [W2B_ELEMS, +W2A_ELEMS)     w2a: offset-conv weights, A-frag order (bf16)
#define W2B_ELEMS (9 * 2 * 4 * 64 * 8)   // 36864
#define W2A_ELEMS (36 * 64 * 8)          // 18432

// LDS window: 8 chunk-planes (8ch) x 6 rows x 128 cols x 16B, padded plane stride.
#define PSTRIDE_B (6 * 128 * 16 + 16)    // 12304 (stride % 128B != 0)
#define SMEM_BYTES (8 * PSTRIDE_B)       // 98432

__device__ __forceinline__ unsigned short f2bf(float f) {
  union { float f; unsigned u; } v; v.f = f;
  unsigned r = v.u + 0x7FFFu + ((v.u >> 16) & 1u);   // RNE
  return (unsigned short)(r >> 16);
}
__device__ __forceinline__ float bf2f(unsigned short h) {
  union { unsigned u; float f; } v; v.u = ((unsigned)h) << 16;
  return v.f;
}
__device__ __forceinline__ unsigned short f2bfh(float f) {   // hot path: HW cvt
  __hip_bfloat16 h = __float2bfloat16(f);
  return *reinterpret_cast<unsigned short*>(&h);
}
// bijective XCD swizzle for 256-block grid (256 % 8 == 0)
__device__ __forceinline__ int swz256(int x) { return (x & 7) * 32 + (x >> 3); }
// XOR-swizzled byte offset of element (row, col) within a plane (16B elements).
// XOR of low-3 element bits with col bits 3..5: stage b32 writes conflict-free,
// b128 reads remain permutation-of-consecutive (conflict-free).
__device__ __forceinline__ int swe(int row, int col) {
  int e = (row << 7) + col;
  e ^= (col >> 3) & 7;
  return e << 4;
}

// ---------------- weight pack ----------------
__global__ __launch_bounds__(256) void pack_w_only(
    const float* __restrict__ wmain, const float* __restrict__ offw,
    unsigned short* __restrict__ ws_u) {
  int idx = blockIdx.x * 256 + threadIdx.x;
  if (idx < W2B_ELEMS) {
    int i = idx & 7, lane = (idx >> 3) & 63, s = (idx >> 9) & 3;
    int mq = (idx >> 11) & 1, t = idx >> 12;
    int o = mq * 32 + (lane & 31);
    int c = 16 * s + (lane >> 5) * 8 + i;
    ws_u[idx] = f2bf(wmain[(o * 64 + c) * 9 + t]);
  } else if (idx < W2B_ELEMS + W2A_ELEMS) {
    int j = idx - W2B_ELEMS;
    int i = j & 7, lane = (j >> 3) & 63, s = j >> 9;   // s 0..35
    int kg = 16 * s + (lane >> 5) * 8 + i;
    int t = kg >> 6, c = kg & 63, oc = lane & 31;
    ws_u[idx] = (oc < OCH_) ? f2bf(offw[(oc * 64 + c) * 9 + t]) : (unsigned short)0;
  }
}

// ---------------- per-tap body: window fast path, wave-uniform global slow path ----------
template<int KI, int KJ>
__device__ __forceinline__ void tap_full(
    float dy, float dx, int ho, int ho0, int px, int lane, int b,
    const char* __restrict__ win, const float* __restrict__ x,
    const unsigned short* __restrict__ wt2,   // w2b + tap*4096 (elements)
    f32x16& acc0, f32x16& acc1) {
  const float ys = (float)(ho - 1 + KI) + dy;
  const float xs = (float)(px - 1 + KJ) + dx;
  const float y0f = floorf(ys), x0f = floorf(xs);
  const int y0 = (int)y0f, x0 = (int)x0f;
  const int y1 = y0 + 1, x1 = x0 + 1;
  const float wy1 = ys - y0f, wx1 = xs - x0f;
  const float wy0 = 1.f - wy1, wx0 = 1.f - wx1;
  const bool vy0 = (unsigned)y0 < (unsigned)H_, vy1 = (unsigned)y1 < (unsigned)H_;
  const bool vx0 = (unsigned)x0 < (unsigned)W_, vx1 = (unsigned)x1 < (unsigned)W_;
  const float g00 = (vy0 && vx0) ? wy0 * wx0 : 0.f;
  const float g01 = (vy0 && vx1) ? wy0 * wx1 : 0.f;
  const float g10 = (vy1 && vx0) ? wy1 * wx0 : 0.f;
  const float g11 = (vy1 && vx1) ? wy1 * wx1 : 0.f;
  const int yc0 = min(max(y0, 0), H_ - 1), yc1 = min(max(y1, 0), H_ - 1);
  const int xc0 = min(max(x0, 0), W_ - 1), xc1 = min(max(x1, 0), W_ - 1);
  const int rr0 = yc0 - ho0 + 2, rr1 = yc1 - ho0 + 2;
  const bool in = ((unsigned)rr0 < 6u) & ((unsigned)rr1 < 6u);
  const int laneh = lane >> 5;

  if (__builtin_expect(__any(!in), 0)) {
    // slow path (|dy| >= ~1): gather from CHW x directly; correct for any offset
    const float* xb = x + (size_t)b * C_ * HW_;
    #pragma unroll 1
    for (int ss = 0; ss < 4; ++ss) {
      short8 bf;
      #pragma unroll
      for (int i = 0; i < 8; ++i) {
        const float* img = xb + (size_t)((2 * ss + laneh) * 8 + i) * HW_;
        float v = g00 * img[yc0 * W_ + xc0] + g01 * img[yc0 * W_ + xc1]
                + g10 * img[yc1 * W_ + xc0] + g11 * img[yc1 * W_ + xc1];
        bf[i] = (short)f2bfh(v);
      }
      const short8 a0 = *(const short8*)&wt2[(ss * 64 + lane) * 8];
      const short8 a1 = *(const short8*)&wt2[((4 + ss) * 64 + lane) * 8];
      acc0 = __builtin_amdgcn_mfma_f32_32x32x16_bf16(a0, bf, acc0, 0, 0, 0);
      acc1 = __builtin_amdgcn_mfma_f32_32x32x16_bf16(a1, bf, acc1, 0, 0, 0);
    }
    return;
  }

  const int u00 = swe(rr0, xc0), u01 = swe(rr0, xc1);
  const int u10 = swe(rr1, xc0), u11 = swe(rr1, xc1);
  #pragma unroll
  for (int ss = 0; ss < 4; ++ss) {
    const char* pb = win + (2 * ss + laneh) * PSTRIDE_B;
    short8 c00 = *(const short8*)(pb + u00);
    short8 c01 = *(const short8*)(pb + u01);
    short8 c10 = *(const short8*)(pb + u10);
    short8 c11 = *(const short8*)(pb + u11);
    short8 bf;
    #pragma unroll
    for (int i = 0; i < 8; ++i) {
      float v = g00 * bf2f((unsigned short)c00[i]) + g01 * bf2f((unsigned short)c01[i])
              + g10 * bf2f((unsigned short)c10[i]) + g11 * bf2f((unsigned short)c11[i]);
      bf[i] = (short)f2bfh(v);
    }
    const short8 a0 = *(const short8*)&wt2[(ss * 64 + lane) * 8];
    const short8 a1 = *(const short8*)&wt2[((4 + ss) * 64 + lane) * 8];
    acc0 = __builtin_amdgcn_mfma_f32_32x32x16_bf16(a0, bf, acc0, 0, 0, 0);
    acc1 = __builtin_amdgcn_mfma_f32_32x32x16_bf16(a1, bf, acc1, 0, 0, 0);
  }
}

// extract dy/dx for tap T from pacc (C/D layout: row=oc=(reg&3)+8*(reg>>2)+4h, col=px)
#define EXT(T)                                                                          \
  {                                                                                     \
    constexpr int ocy = 2 * (T), ocx = 2 * (T) + 1;                                     \
    constexpr int ry = (ocy & 3) + 4 * (ocy >> 3), hy = (ocy >> 2) & 1;                 \
    constexpr int rx = (ocx & 3) + 4 * (ocx >> 3), hx = (ocx >> 2) & 1;                 \
    dys[T] = __shfl(pacc[ry], (lane & 31) + (hy << 5)) + ob[ocy];                       \
    dxs[T] = __shfl(pacc[rx], (lane & 31) + (hx << 5)) + ob[ocx];                       \
  }

#define TAP(KI, KJ)                                                                     \
  tap_full<KI, KJ>(dys[(KI) * 3 + (KJ)], dxs[(KI) * 3 + (KJ)], ho, ho0, px, lane, b,    \
                   smem, x, w2b + ((KI) * 3 + (KJ)) * 4096, acc0, acc1)

// ---------------- fused kernel v6: CHW-direct stage, 2 output rows, 1 barrier ----------
// block=(b, ho0=2*rb): 256 blocks x 512 threads (8 waves).
// wave = (r_off = wave>>2, pair = wave&3): output row ho0+r_off, px strip pair*32..+32.
// After the single stage barrier every wave runs a fully independent stream:
// P1 full-K offset conv (36 MFMA) -> shfl-extract 9 tap offsets -> P2 9 taps full-K.
__global__ __launch_bounds__(512, 2) void deform_fused6(
    const float* __restrict__ x, const float* __restrict__ bias,
    const float* __restrict__ ob, const unsigned short* __restrict__ w2b,
    const unsigned short* __restrict__ w2a, float* __restrict__ out) {
  const int blk = swz256(blockIdx.x);
  const int ho0 = (blk & 63) * 2;
  const int b   = blk >> 6;
  const int tid = threadIdx.x;
  const int lane = tid & 63;
  const int wave = tid >> 6;
  const int r_off = wave >> 2;
  const int pair  = wave & 3;
  const int ho = ho0 + r_off;
  const int px = pair * 32 + (lane & 31);
  const int laneh = lane >> 5;

  __shared__ __align__(16) char smem[SMEM_BYTES];   // 96.1 KB window

  // ---- stage: rows ho0-2..ho0+3 (clamped), all 64 ch, CHW f32 -> bf16 window ----
  const float* xb = x + (size_t)b * C_ * HW_;
  #pragma unroll
  for (int it = 0; it < 12; ++it) {
    const int u = tid + it * 512;          // 6144 units: (cp, row, col4)
    const int cp = u / 192;
    const int rem = u - cp * 192;
    const int row = rem >> 5;
    const int col4 = rem & 31;
    const int srow = min(H_ - 1, max(0, ho0 - 2 + row));
    const int c0 = cp * 2;
    union { float4 v; float f[4]; } fa, fb;
    fa.v = *(const float4*)&xb[(size_t)c0 * HW_ + srow * W_ + col4 * 4];
    fb.v = *(const float4*)&xb[(size_t)(c0 + 1) * HW_ + srow * W_ + col4 * 4];
    char* pl = smem + (cp >> 2) * PSTRIDE_B + ((c0 & 7) << 1);
    #pragma unroll
    for (int j = 0; j < 4; ++j) {
      unsigned pk = (unsigned)f2bfh(fa.f[j]) | ((unsigned)f2bfh(fb.f[j]) << 16);
      *(unsigned*)(pl + swe(row, col4 * 4 + j)) = pk;
    }
  }
  __syncthreads();                         // the only barrier

  // ---- phase 1: offset conv, full K per wave (dual acc chains) ----
  f32x16 pacc_a, pacc_b;
  #pragma unroll
  for (int r = 0; r < 16; ++r) { pacc_a[r] = 0.f; pacc_b[r] = 0.f; }

  #pragma unroll
  for (int s = 0; s < 36; ++s) {
    const int t  = s >> 2;
    const int ki = t / 3, kj = t - 3 * (t / 3);
    const int row = ho - 1 + ki;
    const int col = px - 1 + kj;
    short8 bfr = {0, 0, 0, 0, 0, 0, 0, 0};
    if (((unsigned)row < (unsigned)H_) && ((unsigned)col < (unsigned)W_))
      bfr = *(const short8*)(smem + ((s & 3) * 2 + laneh) * PSTRIDE_B
                             + swe(ki + 1 + r_off, col));
    const short8 afr = *(const short8*)&w2a[((size_t)s * 64 + lane) * 8];
    if (s & 1)
      pacc_b = __builtin_amdgcn_mfma_f32_32x32x16_bf16(afr, bfr, pacc_b, 0, 0, 0);
    else
      pacc_a = __builtin_amdgcn_mfma_f32_32x32x16_bf16(afr, bfr, pacc_a, 0, 0, 0);
  }

  f32x16 pacc;
  #pragma unroll
  for (int r = 0; r < 16; ++r) pacc[r] = pacc_a[r] + pacc_b[r];

  // all 9 taps' offsets, wave-internal via shfl
  float dys[9], dxs[9];
  EXT(0); EXT(1); EXT(2); EXT(3); EXT(4); EXT(5); EXT(6); EXT(7); EXT(8);

  // ---- phase 2: deformable sample + einsum, all 9 taps, full K ----
  f32x16 acc0, acc1;
  #pragma unroll
  for (int r = 0; r < 16; ++r) { acc0[r] = 0.f; acc1[r] = 0.f; }

  TAP(0, 0); TAP(0, 1); TAP(0, 2);
  TAP(1, 0); TAP(1, 1); TAP(1, 2);
  TAP(2, 0); TAP(2, 1); TAP(2, 2);

  // ---- epilogue: direct stores (wave owns full M=64 of its strip) ----
  #pragma unroll
  for (int reg = 0; reg < 16; ++reg) {
    const int row = (reg & 3) + 8 * (reg >> 2) + 4 * laneh;
    out[((b * 64 + row)      * H_ + ho) * W_ + px] = acc0[reg] + bias[row];
    out[((b * 64 + 32 + row) * H_ + ho) * W_ + px] = acc1[reg] + bias[32 + row];
  }
}

extern "C" void kernel_launch(void* const* d_in, const int* in_sizes, int n_in,
                              void* d_out, int out_size, void* d_ws, size_t ws_size,
                              hipStream_t stream) {
  const float* x    = (const float*)d_in[0];
  const float* wt   = (const float*)d_in[1];
  const float* bias = (const float*)d_in[2];
  const float* ow   = (const float*)d_in[3];
  const float* ob   = (const float*)d_in[4];
  float* out = (float*)d_out;

  unsigned short* ws_u = (unsigned short*)d_ws;
  unsigned short* w2b  = ws_u;
  unsigned short* w2a  = ws_u + W2B_ELEMS;

  const int pack_blocks = (W2B_ELEMS + W2A_ELEMS + 255) / 256;   // 216
  pack_w_only<<<pack_blocks, 256, 0, stream>>>(wt, ow, ws_u);

  deform_fused6<<<B_ * (H_ / 2), 512, 0, stream>>>(x, bias, ob, w2b, w2a, out);
}

// Round 11
// 40.382 us; speedup vs baseline: 1.1375x; 1.0022x over previous
//
#include <hip/hip_runtime.h>
#include <hip/hip_bf16.h>

#define B_ 4
#define C_ 64
#define H_ 128
#define W_ 128
#define HW_ (H_ * W_)
#define OCH_ 18

typedef __attribute__((ext_vector_type(8))) short short8;
typedef __attribute__((ext_vector_type(16))) float f32x16;
typedef __attribute__((ext_vector_type(2))) float float2v;

// ws layout (elements of unsigned short):
//   [0, W2B_ELEMS)              w2b: main weights, A-frag order (bf16)
//   [W2B_ELEMS, +W2A_ELEMS)     w2a: offset-conv weights, A-frag order (bf16)
#define W2B_ELEMS (9 * 2 * 4 * 64 * 8)   // 36864
#define W2A_ELEMS (36 * 64 * 8)          // 18432

// LDS window: 8 chunk-planes (8ch) x 6 rows x 128 cols x 16B, padded plane stride.
// Linear layout: reads/writes are b128 at 16B lane stride = natural conflict-free.
#define PSTRIDE_B (6 * 128 * 16 + 16)    // 12304
#define SMEM_BYTES (8 * PSTRIDE_B)       // 98432

__device__ __forceinline__ unsigned short f2bf(float f) {
  union { float f; unsigned u; } v; v.f = f;
  unsigned r = v.u + 0x7FFFu + ((v.u >> 16) & 1u);   // RNE
  return (unsigned short)(r >> 16);
}
__device__ __forceinline__ float bf2f(unsigned short h) {
  union { unsigned u; float f; } v; v.u = ((unsigned)h) << 16;
  return v.f;
}
__device__ __forceinline__ unsigned short f2bfh(float f) {   // hot path: HW cvt
  __hip_bfloat16 h = __float2bfloat16(f);
  return *reinterpret_cast<unsigned short*>(&h);
}
__device__ __forceinline__ float uaf(unsigned u) {
  union { unsigned u; float f; } v; v.u = u; return v.f;
}
// bijective XCD swizzle for 256-block grid (256 % 8 == 0)
__device__ __forceinline__ int swz256(int x) { return (x & 7) * 32 + (x >> 3); }

// ---------------- weight pack ----------------
__global__ __launch_bounds__(256) void pack_w_only(
    const float* __restrict__ wmain, const float* __restrict__ offw,
    unsigned short* __restrict__ ws_u) {
  int idx = blockIdx.x * 256 + threadIdx.x;
  if (idx < W2B_ELEMS) {
    int i = idx & 7, lane = (idx >> 3) & 63, s = (idx >> 9) & 3;
    int mq = (idx >> 11) & 1, t = idx >> 12;
    int o = mq * 32 + (lane & 31);
    int c = 16 * s + (lane >> 5) * 8 + i;
    ws_u[idx] = f2bf(wmain[(o * 64 + c) * 9 + t]);
  } else if (idx < W2B_ELEMS + W2A_ELEMS) {
    int j = idx - W2B_ELEMS;
    int i = j & 7, lane = (j >> 3) & 63, s = j >> 9;   // s 0..35
    int kg = 16 * s + (lane >> 5) * 8 + i;
    int t = kg >> 6, c = kg & 63, oc = lane & 31;
    ws_u[idx] = (oc < OCH_) ? f2bf(offw[(oc * 64 + c) * 9 + t]) : (unsigned short)0;
  }
}

// ---------------- per-tap body: hoisted window reads, packed-f32 blend ----------------
template<int KI, int KJ>
__device__ __forceinline__ void tap_full(
    float dy, float dx, int ho, int ho0, int px, int lane, int b,
    const char* __restrict__ win, const float* __restrict__ x,
    const unsigned short* __restrict__ wt2,   // w2b + tap*4096 (elements)
    f32x16& acc0, f32x16& acc1) {
  const float ys = (float)(ho - 1 + KI) + dy;
  const float xs = (float)(px - 1 + KJ) + dx;
  const float y0f = floorf(ys), x0f = floorf(xs);
  const int y0 = (int)y0f, x0 = (int)x0f;
  const int y1 = y0 + 1, x1 = x0 + 1;
  const float wy1 = ys - y0f, wx1 = xs - x0f;
  const float wy0 = 1.f - wy1, wx0 = 1.f - wx1;
  const bool vy0 = (unsigned)y0 < (unsigned)H_, vy1 = (unsigned)y1 < (unsigned)H_;
  const bool vx0 = (unsigned)x0 < (unsigned)W_, vx1 = (unsigned)x1 < (unsigned)W_;
  const float g00 = (vy0 && vx0) ? wy0 * wx0 : 0.f;
  const float g01 = (vy0 && vx1) ? wy0 * wx1 : 0.f;
  const float g10 = (vy1 && vx0) ? wy1 * wx0 : 0.f;
  const float g11 = (vy1 && vx1) ? wy1 * wx1 : 0.f;
  const int yc0 = min(max(y0, 0), H_ - 1), yc1 = min(max(y1, 0), H_ - 1);
  const int xc0 = min(max(x0, 0), W_ - 1), xc1 = min(max(x1, 0), W_ - 1);
  const int rr0 = yc0 - ho0 + 2, rr1 = yc1 - ho0 + 2;
  const bool in = ((unsigned)rr0 < 6u) & ((unsigned)rr1 < 6u);
  const int laneh = lane >> 5;

  if (__builtin_expect(__any(!in), 0)) {
    // slow path (|dy| >= ~1): gather from CHW x directly; correct for any offset
    const float* xb = x + (size_t)b * C_ * HW_;
    #pragma unroll 1
    for (int ss = 0; ss < 4; ++ss) {
      short8 bf;
      #pragma unroll
      for (int i = 0; i < 8; ++i) {
        const float* img = xb + (size_t)((2 * ss + laneh) * 8 + i) * HW_;
        float v = g00 * img[yc0 * W_ + xc0] + g01 * img[yc0 * W_ + xc1]
                + g10 * img[yc1 * W_ + xc0] + g11 * img[yc1 * W_ + xc1];
        bf[i] = (short)f2bfh(v);
      }
      const short8 a0 = *(const short8*)&wt2[(ss * 64 + lane) * 8];
      const short8 a1 = *(const short8*)&wt2[((4 + ss) * 64 + lane) * 8];
      acc0 = __builtin_amdgcn_mfma_f32_32x32x16_bf16(a0, bf, acc0, 0, 0, 0);
      acc1 = __builtin_amdgcn_mfma_f32_32x32x16_bf16(a1, bf, acc1, 0, 0, 0);
    }
    return;
  }

  const int u00 = ((rr0 << 7) + xc0) << 4, u01 = ((rr0 << 7) + xc1) << 4;
  const int u10 = ((rr1 << 7) + xc0) << 4, u11 = ((rr1 << 7) + xc1) << 4;

  // hoist all 16 corner reads (independent b128s, 16B lane stride = conflict-free)
  short8 c00[4], c01[4], c10[4], c11[4];
  #pragma unroll
  for (int ss = 0; ss < 4; ++ss) {
    const char* pb = win + (2 * ss + laneh) * PSTRIDE_B;
    c00[ss] = *(const short8*)(pb + u00);
    c01[ss] = *(const short8*)(pb + u01);
    c10[ss] = *(const short8*)(pb + u10);
    c11[ss] = *(const short8*)(pb + u11);
  }

  #pragma unroll
  for (int ss = 0; ss < 4; ++ss) {
    short8 bf;
    #pragma unroll
    for (int d = 0; d < 4; ++d) {               // packed 2-wide f32 blend per dword
      const unsigned w00 = ((const unsigned*)&c00[ss])[d];
      const unsigned w01 = ((const unsigned*)&c01[ss])[d];
      const unsigned w10 = ((const unsigned*)&c10[ss])[d];
      const unsigned w11 = ((const unsigned*)&c11[ss])[d];
      float2v p00, p01, p10, p11;
      p00.x = uaf(w00 << 16); p00.y = uaf(w00 & 0xFFFF0000u);
      p01.x = uaf(w01 << 16); p01.y = uaf(w01 & 0xFFFF0000u);
      p10.x = uaf(w10 << 16); p10.y = uaf(w10 & 0xFFFF0000u);
      p11.x = uaf(w11 << 16); p11.y = uaf(w11 & 0xFFFF0000u);
      float2v v = p00 * g00 + p01 * g01 + p10 * g10 + p11 * g11;
      ((unsigned*)&bf)[d] = (unsigned)f2bfh(v.x) | ((unsigned)f2bfh(v.y) << 16);
    }
    const short8 a0 = *(const short8*)&wt2[(ss * 64 + lane) * 8];
    const short8 a1 = *(const short8*)&wt2[((4 + ss) * 64 + lane) * 8];
    acc0 = __builtin_amdgcn_mfma_f32_32x32x16_bf16(a0, bf, acc0, 0, 0, 0);
    acc1 = __builtin_amdgcn_mfma_f32_32x32x16_bf16(a1, bf, acc1, 0, 0, 0);
  }
}

// extract dy/dx for tap T from pacc (C/D layout: row=oc=(reg&3)+8*(reg>>2)+4h, col=px)
#define EXT(T)                                                                          \
  {                                                                                     \
    constexpr int ocy = 2 * (T), ocx = 2 * (T) + 1;                                     \
    constexpr int ry = (ocy & 3) + 4 * (ocy >> 3), hy = (ocy >> 2) & 1;                 \
    constexpr int rx = (ocx & 3) + 4 * (ocx >> 3), hx = (ocx >> 2) & 1;                 \
    dys[T] = __shfl(pacc[ry], (lane & 31) + (hy << 5)) + ob[ocy];                       \
    dxs[T] = __shfl(pacc[rx], (lane & 31) + (hx << 5)) + ob[ocx];                       \
  }

#define TAP(KI, KJ)                                                                     \
  tap_full<KI, KJ>(dys[(KI) * 3 + (KJ)], dxs[(KI) * 3 + (KJ)], ho, ho0, px, lane, b,    \
                   smem, x, w2b + ((KI) * 3 + (KJ)) * 4096, acc0, acc1)

// ---------------- fused kernel v7: transpose-in-reg stage (b128 writes), 1 barrier ------
// block=(b, ho0=2*rb): 256 blocks x 512 threads (8 waves).
// wave = (r_off = wave>>2, pair = wave&3): output row ho0+r_off, px strip pair*32..+32.
__global__ __launch_bounds__(512, 2) void deform_fused7(
    const float* __restrict__ x, const float* __restrict__ bias,
    const float* __restrict__ ob, const unsigned short* __restrict__ w2b,
    const unsigned short* __restrict__ w2a, float* __restrict__ out) {
  const int blk = swz256(blockIdx.x);
  const int ho0 = (blk & 63) * 2;
  const int b   = blk >> 6;
  const int tid = threadIdx.x;
  const int lane = tid & 63;
  const int wave = tid >> 6;
  const int r_off = wave >> 2;
  const int pair  = wave & 3;
  const int ho = ho0 + r_off;
  const int px = pair * 32 + (lane & 31);
  const int laneh = lane >> 5;

  __shared__ __align__(16) char smem[SMEM_BYTES];   // 96.1 KB window

  // ---- stage: rows ho0-2..ho0+3 (clamped), 8ch x 4col per unit, reg transpose ----
  // unit u = [row(6)][p(8)][col4(32)]; global loads: 8x float4 coalesced (1KB/instr);
  // LDS writes: 4x ds_write_b128 at 16B lane stride (conflict-free).
  const float* xb = x + (size_t)b * C_ * HW_;
  #pragma unroll
  for (int it = 0; it < 3; ++it) {
    const int u = tid + it * 512;          // 1536 units
    const int row  = u >> 8;
    const int p    = (u >> 5) & 7;
    const int col4 = u & 31;
    const int srow = min(H_ - 1, max(0, ho0 - 2 + row));
    const float* bp = xb + (size_t)(p * 8) * HW_ + srow * W_ + col4 * 4;
    float4 f[8];
    #pragma unroll
    for (int i = 0; i < 8; ++i) f[i] = *(const float4*)(bp + (size_t)i * HW_);
    char* outb = smem + p * PSTRIDE_B + (((row << 7) + col4 * 4) << 4);
    #pragma unroll
    for (int j = 0; j < 4; ++j) {
      short8 v;
      #pragma unroll
      for (int i = 0; i < 8; ++i)
        v[i] = (short)f2bfh(reinterpret_cast<const float*>(&f[i])[j]);
      *(short8*)(outb + j * 16) = v;
    }
  }
  __syncthreads();                         // the only barrier

  // ---- phase 1: offset conv, full K per wave (dual acc chains) ----
  f32x16 pacc_a, pacc_b;
  #pragma unroll
  for (int r = 0; r < 16; ++r) { pacc_a[r] = 0.f; pacc_b[r] = 0.f; }

  #pragma unroll
  for (int s = 0; s < 36; ++s) {
    const int t  = s >> 2;
    const int ki = t / 3, kj = t - 3 * (t / 3);
    const int row = ho - 1 + ki;
    const int col = px - 1 + kj;
    short8 bfr = {0, 0, 0, 0, 0, 0, 0, 0};
    if (((unsigned)row < (unsigned)H_) && ((unsigned)col < (unsigned)W_))
      bfr = *(const short8*)(smem + ((s & 3) * 2 + laneh) * PSTRIDE_B
                             + ((((ki + 1 + r_off) << 7) + col) << 4));
    const short8 afr = *(const short8*)&w2a[((size_t)s * 64 + lane) * 8];
    if (s & 1)
      pacc_b = __builtin_amdgcn_mfma_f32_32x32x16_bf16(afr, bfr, pacc_b, 0, 0, 0);
    else
      pacc_a = __builtin_amdgcn_mfma_f32_32x32x16_bf16(afr, bfr, pacc_a, 0, 0, 0);
  }

  f32x16 pacc;
  #pragma unroll
  for (int r = 0; r < 16; ++r) pacc[r] = pacc_a[r] + pacc_b[r];

  // all 9 taps' offsets, wave-internal via shfl
  float dys[9], dxs[9];
  EXT(0); EXT(1); EXT(2); EXT(3); EXT(4); EXT(5); EXT(6); EXT(7); EXT(8);

  // ---- phase 2: deformable sample + einsum, all 9 taps, full K ----
  f32x16 acc0, acc1;
  #pragma unroll
  for (int r = 0; r < 16; ++r) { acc0[r] = 0.f; acc1[r] = 0.f; }

  TAP(0, 0); TAP(0, 1); TAP(0, 2);
  TAP(1, 0); TAP(1, 1); TAP(1, 2);
  TAP(2, 0); TAP(2, 1); TAP(2, 2);

  // ---- epilogue: direct stores (wave owns full M=64 of its strip) ----
  #pragma unroll
  for (int reg = 0; reg < 16; ++reg) {
    const int row = (reg & 3) + 8 * (reg >> 2) + 4 * laneh;
    out[((b * 64 + row)      * H_ + ho) * W_ + px] = acc0[reg] + bias[row];
    out[((b * 64 + 32 + row) * H_ + ho) * W_ + px] = acc1[reg] + bias[32 + row];
  }
}

extern "C" void kernel_launch(void* const* d_in, const int* in_sizes, int n_in,
                              void* d_out, int out_size, void* d_ws, size_t ws_size,
                              hipStream_t stream) {
  const float* x    = (const float*)d_in[0];
  const float* wt   = (const float*)d_in[1];
  const float* bias = (const float*)d_in[2];
  const float* ow   = (const float*)d_in[3];
  const float* ob   = (const float*)d_in[4];
  float* out = (float*)d_out;

  unsigned short* ws_u = (unsigned short*)d_ws;
  unsigned short* w2b  = ws_u;
  unsigned short* w2a  = ws_u + W2B_ELEMS;

  const int pack_blocks = (W2B_ELEMS + W2A_ELEMS + 255) / 256;   // 216
  pack_w_only<<<pack_blocks, 256, 0, stream>>>(wt, ow, ws_u);

  deform_fused7<<<B_ * (H_ / 2), 512, 0, stream>>>(x, bias, ob, w2b, w2a, out);
}